// Round 3
// baseline (675.244 us; speedup 1.0000x reference)
//
#include <hip/hip_runtime.h>

#define NN 20000
#define NE 320000
#define CC 128
#define SS 10
#define NWIN 5000  // NN/4 windows of 4 nodes

typedef __attribute__((ext_vector_type(8))) short short8;
typedef __attribute__((ext_vector_type(4))) float f32x4;

#define MFMA16(a, b, c) __builtin_amdgcn_mfma_f32_16x16x32_bf16(a, b, c, 0, 0, 0)

__device__ __forceinline__ float silu_f(float x) { return x / (1.f + __expf(-x)); }

__device__ __forceinline__ unsigned short f2bf(float x) {  // RNE float->bf16 bits
  unsigned u = __float_as_uint(x);
  unsigned r = u + 0x7FFFu + ((u >> 16) & 1u);
  return (unsigned short)(r >> 16);
}
__device__ __forceinline__ float bf2f(unsigned short h) {
  return __uint_as_float(((unsigned)h) << 16);
}

// ---------------- prep: W2 -> transposed bf16 hi/lo [col][k] ----------------
__global__ __launch_bounds__(256) void k_prep_w2(const float* __restrict__ W2,
                                                 unsigned short* __restrict__ w2h,
                                                 unsigned short* __restrict__ w2l) {
  const int i = blockIdx.x * 256 + threadIdx.x;  // grid 64 -> 16384
  if (i < 64 * 256) {
    const int col = i % 256, k = i / 256;  // i == k*256+col
    const float x = W2[i];
    const unsigned short h = f2bf(x);
    w2h[col * 64 + k] = h;
    w2l[col * 64 + k] = f2bf(x - bf2f(h));
  }
}

// ---------------- h = node_feats @ W_up, 8 nodes per 128-thread block ----------------
__global__ __launch_bounds__(128) void k_node_h(const float* __restrict__ nf,
                                                const float* __restrict__ W,
                                                float* __restrict__ h) {
  __shared__ __align__(16) float rows[8][CC];
  const int c = threadIdx.x;
  const int n0 = blockIdx.x * 8;
#pragma unroll
  for (int q = 0; q < 8; ++q) rows[q][c] = nf[(n0 + q) * CC + c];
  __syncthreads();
  float acc[8] = {0.f, 0.f, 0.f, 0.f, 0.f, 0.f, 0.f, 0.f};
  for (int k = 0; k < CC; k += 4) {
    const float w0 = W[(k + 0) * CC + c];
    const float w1 = W[(k + 1) * CC + c];
    const float w2 = W[(k + 2) * CC + c];
    const float w3 = W[(k + 3) * CC + c];
#pragma unroll
    for (int q = 0; q < 8; ++q) {
      float4 v = *(const float4*)&rows[q][k];
      acc[q] += v.x * w0 + v.y * w1 + v.z * w2 + v.w * w3;
    }
  }
#pragma unroll
  for (int q = 0; q < 8; ++q) h[(n0 + q) * CC + c] = acc[q];
}

// ---------------- CSR build ----------------
__global__ void k_hist(const int* __restrict__ recv, int* __restrict__ cnt) {
  int i = blockIdx.x * blockDim.x + threadIdx.x;
  if (i < NE) atomicAdd(&cnt[recv[i]], 1);
}

// Single block, 1024 threads; each thread scans 20 contiguous counts.
// cntcur is read as counts and overwritten in place with the exclusive prefix.
__global__ __launch_bounds__(1024) void k_scan2(int* cntcur, int* offs) {
  const int t = threadIdx.x;
  int v[20];
  int tot = 0;
  if (t < 1000) {
#pragma unroll
    for (int i = 0; i < 20; ++i) {
      v[i] = cntcur[t * 20 + i];
      tot += v[i];
    }
  }
  const int lane = t & 63;
  int x = tot;
#pragma unroll
  for (int off = 1; off < 64; off <<= 1) {
    int y = __shfl_up(x, off, 64);
    if (lane >= off) x += y;
  }
  __shared__ int wt[16], wo[16];
  if (lane == 63) wt[t >> 6] = x;
  __syncthreads();
  if (t == 0) {
    int a = 0;
    for (int w = 0; w < 16; ++w) {
      wo[w] = a;
      a += wt[w];
    }
    offs[NN] = a;
  }
  __syncthreads();
  int run = wo[t >> 6] + x - tot;
  if (t < 1000) {
#pragma unroll
    for (int i = 0; i < 20; ++i) {
      offs[t * 20 + i] = run;
      cntcur[t * 20 + i] = run;
      run += v[i];
    }
  }
}

__global__ void k_fill(const int* __restrict__ recv, int* __restrict__ cur,
                       int* __restrict__ ord) {
  int i = blockIdx.x * blockDim.x + threadIdx.x;
  if (i < NE) {
    int r = recv[i];
    int pos = atomicAdd(&cur[r], 1);
    ord[pos] = i;
  }
}

// ---------------- dense edge aggregation ----------------
// One block per window of 4 consecutive nodes (receiver-sorted CSR). Edges
// processed in dense 64-edge passes: stage -> hid(16x..., bf16 hi/lo to LDS)
// -> per-wave MFMA (wave owns 32 cols of BOTH w0 and w1; W2 frags in regs)
// -> consume: gather h[sender], multiply, run-compressed ds_add into the
// 4-node LDS accumulator. Flush with plain coalesced stores (nodes are
// block-exclusive). 3 barriers per 64 edges.
__global__ __launch_bounds__(256, 3) void k_edge_dense(
    const float* __restrict__ vectors, const float* __restrict__ lengths,
    const float* __restrict__ efeat, const int* __restrict__ senders,
    const float* __restrict__ hbuf, const float* __restrict__ W1,
    const float* __restrict__ B1, const unsigned short* __restrict__ w2h,
    const unsigned short* __restrict__ w2l, const int* __restrict__ offs,
    const int* __restrict__ ord, float* __restrict__ sout) {
  __shared__ __align__(16) float W1s[9 * 64];
  __shared__ __align__(16) float B1s[64];
  __shared__ __align__(16) float ed[64][20];            // y1(3), len, efeat(8); pad to 20
  __shared__ __align__(16) unsigned short hidh[64][72]; // bf16 hi, row pad 72
  __shared__ __align__(16) unsigned short hidl[64][72]; // bf16 lo
  __shared__ __align__(16) float ldsacc[4][4][CC];      // [node][s0,sx,sy,sz][c]
  __shared__ int snd_l[64];
  __shared__ int rl_l[64];

  const int t = threadIdx.x;
  const int l = t & 63, wv = t >> 6, lg = l >> 4, lm = l & 15;

  for (int i = t; i < 576; i += 256) W1s[i] = W1[i];
  if (t < 64) B1s[t] = B1[t];
  {
    float* la = &ldsacc[0][0][0];
    for (int i = t; i < 2048; i += 256) la[i] = 0.f;
  }

  // W2 B-fragments in registers: [wpart][ct2][s]; col = wpart*128 + wv*32 + ct2*16 + lm
  short8 Bh[2][2][2], Bl[2][2][2];
#pragma unroll
  for (int wp = 0; wp < 2; ++wp)
#pragma unroll
    for (int c2 = 0; c2 < 2; ++c2)
#pragma unroll
      for (int s = 0; s < 2; ++s) {
        const int col = wp * 128 + wv * 32 + c2 * 16 + lm;
        Bh[wp][c2][s] = *(const short8*)&w2h[col * 64 + s * 32 + lg * 8];
        Bl[wp][c2][s] = *(const short8*)&w2l[col * 64 + s * 32 + lg * 8];
      }

  const int nb = blockIdx.x * 4;
  const int o0 = offs[nb], o1 = offs[nb + 1], o2 = offs[nb + 2];
  const int o3 = offs[nb + 3], o4 = offs[nb + 4];
  const int npass = (o4 - o0 + 63) >> 6;

  for (int p = 0; p < npass; ++p) {
    const int base = o0 + p * 64;
    const int cnt = min(64, o4 - base);
    __syncthreads();  // protect LDS reuse from previous pass
    {  // stage 64 edges, 4 threads each
      const int slot = t >> 2, part = t & 3;
      const int pos = base + slot;
      const bool live = slot < cnt;
      const int eid = live ? ord[pos] : 0;
      if (part == 0) {
        float vx = 0.f, vy = 0.f, vz = 0.f, ln = 0.f;
        if (live) {
          vx = vectors[eid * 3 + 0];
          vy = vectors[eid * 3 + 1];
          vz = vectors[eid * 3 + 2];
          ln = lengths[eid];
        }
        const float nr = sqrtf(vx * vx + vy * vy + vz * vz) + 1e-9f;
        const float sc = 1.7320508075688772f / nr;
        ed[slot][0] = vx * sc;
        ed[slot][1] = vy * sc;
        ed[slot][2] = vz * sc;
        ed[slot][3] = ln;
      } else if (part == 1) {
        float4 v = {0.f, 0.f, 0.f, 0.f};
        if (live) v = *(const float4*)&efeat[eid * 8];
        ed[slot][4] = v.x; ed[slot][5] = v.y; ed[slot][6] = v.z; ed[slot][7] = v.w;
      } else if (part == 2) {
        float4 v = {0.f, 0.f, 0.f, 0.f};
        if (live) v = *(const float4*)&efeat[eid * 8 + 4];
        ed[slot][8] = v.x; ed[slot][9] = v.y; ed[slot][10] = v.z; ed[slot][11] = v.w;
      } else {
        snd_l[slot] = live ? senders[eid] : 0;
        rl_l[slot] = (pos >= o1) + (pos >= o2) + (pos >= o3);
      }
    }
    __syncthreads();
    {  // hid: thread t -> edge e = t&63, k-range [kseg*16, kseg*16+16)
      const int e = t & 63, kseg = t >> 6;
      float ef[9];
#pragma unroll
      for (int r = 0; r < 8; ++r) ef[r] = ed[e][4 + r];
      ef[8] = ed[e][3];
      const bool live = e < cnt;
      short8 oh0, oh1, ol0, ol1;
#pragma unroll
      for (int q = 0; q < 4; ++q) {
        float4 x = *(const float4*)&B1s[kseg * 16 + q * 4];
#pragma unroll
        for (int r = 0; r < 9; ++r) {
          float4 w = *(const float4*)&W1s[r * 64 + kseg * 16 + q * 4];
          x.x += ef[r] * w.x; x.y += ef[r] * w.y;
          x.z += ef[r] * w.z; x.w += ef[r] * w.w;
        }
        float s0v = live ? silu_f(x.x) : 0.f;
        float s1v = live ? silu_f(x.y) : 0.f;
        float s2v = live ? silu_f(x.z) : 0.f;
        float s3v = live ? silu_f(x.w) : 0.f;
        unsigned short h0 = f2bf(s0v), h1 = f2bf(s1v), h2 = f2bf(s2v), h3 = f2bf(s3v);
        unsigned short g0 = f2bf(s0v - bf2f(h0)), g1 = f2bf(s1v - bf2f(h1));
        unsigned short g2 = f2bf(s2v - bf2f(h2)), g3 = f2bf(s3v - bf2f(h3));
        if (q < 2) {
          oh0[q * 4 + 0] = (short)h0; oh0[q * 4 + 1] = (short)h1;
          oh0[q * 4 + 2] = (short)h2; oh0[q * 4 + 3] = (short)h3;
          ol0[q * 4 + 0] = (short)g0; ol0[q * 4 + 1] = (short)g1;
          ol0[q * 4 + 2] = (short)g2; ol0[q * 4 + 3] = (short)g3;
        } else {
          oh1[(q - 2) * 4 + 0] = (short)h0; oh1[(q - 2) * 4 + 1] = (short)h1;
          oh1[(q - 2) * 4 + 2] = (short)h2; oh1[(q - 2) * 4 + 3] = (short)h3;
          ol1[(q - 2) * 4 + 0] = (short)g0; ol1[(q - 2) * 4 + 1] = (short)g1;
          ol1[(q - 2) * 4 + 2] = (short)g2; ol1[(q - 2) * 4 + 3] = (short)g3;
        }
      }
      *(short8*)&hidh[e][kseg * 16] = oh0;
      *(short8*)&hidh[e][kseg * 16 + 8] = oh1;
      *(short8*)&hidl[e][kseg * 16] = ol0;
      *(short8*)&hidl[e][kseg * 16 + 8] = ol1;
    }
    __syncthreads();
    // per-wave MFMA + consume over the 4 sub-chunks
#pragma unroll 1
    for (int sc = 0; sc < 4; ++sc) {
      short8 Ah0 = *(const short8*)&hidh[sc * 16 + lm][lg * 8];
      short8 Ah1 = *(const short8*)&hidh[sc * 16 + lm][32 + lg * 8];
      short8 Al0 = *(const short8*)&hidl[sc * 16 + lm][lg * 8];
      short8 Al1 = *(const short8*)&hidl[sc * 16 + lm][32 + lg * 8];
      f32x4 a0[2], a1[2];
#pragma unroll
      for (int c2 = 0; c2 < 2; ++c2) {
        a0[c2] = (f32x4){0.f, 0.f, 0.f, 0.f};
        a1[c2] = (f32x4){0.f, 0.f, 0.f, 0.f};
      }
#pragma unroll
      for (int c2 = 0; c2 < 2; ++c2) {
        a0[c2] = MFMA16(Ah0, Bh[0][c2][0], a0[c2]);
        a0[c2] = MFMA16(Ah0, Bl[0][c2][0], a0[c2]);
        a0[c2] = MFMA16(Al0, Bh[0][c2][0], a0[c2]);
        a0[c2] = MFMA16(Ah1, Bh[0][c2][1], a0[c2]);
        a0[c2] = MFMA16(Ah1, Bl[0][c2][1], a0[c2]);
        a0[c2] = MFMA16(Al1, Bh[0][c2][1], a0[c2]);
        a1[c2] = MFMA16(Ah0, Bh[1][c2][0], a1[c2]);
        a1[c2] = MFMA16(Ah0, Bl[1][c2][0], a1[c2]);
        a1[c2] = MFMA16(Al0, Bh[1][c2][0], a1[c2]);
        a1[c2] = MFMA16(Ah1, Bh[1][c2][1], a1[c2]);
        a1[c2] = MFMA16(Ah1, Bl[1][c2][1], a1[c2]);
        a1[c2] = MFMA16(Al1, Bh[1][c2][1], a1[c2]);
      }
      // consume: C/D layout col=lane&15, row=lg*4+reg [m89/m91-verified]
      const int row0 = sc * 16 + lg * 4;
      int sd[4], rl[4];
      float ya[4], yb[4], yc[4];
#pragma unroll
      for (int r = 0; r < 4; ++r) {
        sd[r] = snd_l[row0 + r];
        rl[r] = rl_l[row0 + r];
        ya[r] = ed[row0 + r][0];
        yb[r] = ed[row0 + r][1];
        yc[r] = ed[row0 + r][2];
      }
#pragma unroll
      for (int c2 = 0; c2 < 2; ++c2) {
        const int c = wv * 32 + c2 * 16 + lm;
        float hc[4];
#pragma unroll
        for (int r = 0; r < 4; ++r) hc[r] = hbuf[(size_t)sd[r] * CC + c];
        {  // s0, run-compressed
          float run = a0[c2][0] * hc[0];
#pragma unroll
          for (int r = 1; r < 4; ++r) {
            const float v = a0[c2][r] * hc[r];
            if (rl[r] != rl[r - 1]) {
              atomicAdd(&ldsacc[rl[r - 1]][0][c], run);
              run = v;
            } else {
              run += v;
            }
          }
          atomicAdd(&ldsacc[rl[3]][0][c], run);
        }
        {  // s1 (x,y,z), run-compressed
          const float m0 = a1[c2][0] * hc[0];
          float rx = m0 * ya[0], ry = m0 * yb[0], rz = m0 * yc[0];
#pragma unroll
          for (int r = 1; r < 4; ++r) {
            const float m = a1[c2][r] * hc[r];
            if (rl[r] != rl[r - 1]) {
              atomicAdd(&ldsacc[rl[r - 1]][1][c], rx);
              atomicAdd(&ldsacc[rl[r - 1]][2][c], ry);
              atomicAdd(&ldsacc[rl[r - 1]][3][c], rz);
              rx = m * ya[r]; ry = m * yb[r]; rz = m * yc[r];
            } else {
              rx += m * ya[r]; ry += m * yb[r]; rz += m * yc[r];
            }
          }
          atomicAdd(&ldsacc[rl[3]][1][c], rx);
          atomicAdd(&ldsacc[rl[3]][2][c], ry);
          atomicAdd(&ldsacc[rl[3]][3][c], rz);
        }
      }
    }
  }
  __syncthreads();
  const float inv = 1.f / 16.f;
  for (int i = t; i < 2048; i += 256) {
    const int j = i >> 9, rest = i & 511;
    sout[(size_t)(nb + j) * 512 + rest] = ldsacc[j][rest >> 7][rest & 127] * inv;
  }
}

// ---------------- fused downstream: 8 nodes per 256-thread block ----------------
__global__ __launch_bounds__(256) void k_down(
    const float* __restrict__ sbuf, const float* __restrict__ attrs,
    const float* __restrict__ Wd0, const float* __restrict__ Wd1,
    const float* __restrict__ Wprod0, const float* __restrict__ Wprod1,
    const float* __restrict__ Wp0, const float* __restrict__ Wp1,
    const float* __restrict__ Wr1, const float* __restrict__ Wr2,
    const float* __restrict__ Wg, const float* __restrict__ wv,
    float* __restrict__ out_scalars, float* __restrict__ out_vec,
    float* __restrict__ out_nf) {
  __shared__ __align__(16) float X[8][4][CC];  // s, then b
  __shared__ __align__(16) float Y[8][4][CC];  // a, then h
  __shared__ float at_s[8][SS];
  __shared__ float mh_s[8][16];
  __shared__ float gate_s[8];
  const int t = threadIdx.x;
  const int c = t & 127, p = t >> 7;
  const int n0 = blockIdx.x * 8;
  float* Xf = &X[0][0][0];
  float* Yf = &Y[0][0][0];
  for (int i = t; i < 4096; i += 256) Xf[i] = sbuf[(size_t)n0 * 512 + i];
  for (int i = t; i < 8 * SS; i += 256) at_s[i / SS][i % SS] = attrs[n0 * SS + i];
  __syncthreads();
  // ---- stage A: a = s @ [Wd0 | Wd1] ----
  {
    float acc[4][4];
#pragma unroll
    for (int q = 0; q < 4; ++q)
#pragma unroll
      for (int m = 0; m < 4; ++m) acc[q][m] = 0.f;
    for (int k = 0; k < CC; k += 4) {
      const float a0 = Wd0[(k + 0) * CC + c], a1 = Wd0[(k + 1) * CC + c];
      const float a2 = Wd0[(k + 2) * CC + c], a3 = Wd0[(k + 3) * CC + c];
      const float b0 = Wd1[(k + 0) * CC + c], b1 = Wd1[(k + 1) * CC + c];
      const float b2 = Wd1[(k + 2) * CC + c], b3 = Wd1[(k + 3) * CC + c];
#pragma unroll
      for (int q = 0; q < 4; ++q) {
        const int nb = p * 4 + q;
        float4 v0 = *(const float4*)&X[nb][0][k];
        acc[q][0] += v0.x * a0 + v0.y * a1 + v0.z * a2 + v0.w * a3;
#pragma unroll
        for (int m = 1; m < 4; ++m) {
          float4 u = *(const float4*)&X[nb][m][k];
          acc[q][m] += u.x * b0 + u.y * b1 + u.z * b2 + u.w * b3;
        }
      }
    }
#pragma unroll
    for (int q = 0; q < 4; ++q)
#pragma unroll
      for (int m = 0; m < 4; ++m) Y[p * 4 + q][m][c] = acc[q][m];
  }
  __syncthreads();
  // ---- stage B: pointwise paths / species product (X := b) ----
#pragma unroll
  for (int q = 0; q < 4; ++q) {
    const int nb = p * 4 + q;
    const float a0 = Y[nb][0][c];
    const float ax = Y[nb][1][c], ay = Y[nb][2][c], az = Y[nb][3][c];
    const float dot = ax * ax + ay * ay + az * az;
    int sidx = 0;
#pragma unroll
    for (int si = 0; si < SS; ++si)
      if (at_s[nb][si] > 0.5f) sidx = si;
    const float a0sq = a0 * a0;
    const float b0v = Wprod0[(sidx * 5 + 0) * CC + c] * a0 +
                      Wprod0[(sidx * 5 + 1) * CC + c] * a0sq +
                      Wprod0[(sidx * 5 + 2) * CC + c] * dot +
                      Wprod0[(sidx * 5 + 3) * CC + c] * (a0sq * a0) +
                      Wprod0[(sidx * 5 + 4) * CC + c] * (a0 * dot);
    const float fac = Wprod1[(sidx * 4 + 0) * CC + c] +
                      Wprod1[(sidx * 4 + 1) * CC + c] * a0 +
                      Wprod1[(sidx * 4 + 2) * CC + c] * a0sq +
                      Wprod1[(sidx * 4 + 3) * CC + c] * dot;
    X[nb][0][c] = b0v;
    X[nb][1][c] = ax * fac;
    X[nb][2][c] = ay * fac;
    X[nb][3][c] = az * fac;
  }
  __syncthreads();
  // ---- stage H: h = b @ [Wp0 | Wp1] (Y := h) ----
  {
    float acc[4][4];
#pragma unroll
    for (int q = 0; q < 4; ++q)
#pragma unroll
      for (int m = 0; m < 4; ++m) acc[q][m] = 0.f;
    for (int k = 0; k < CC; k += 4) {
      const float a0 = Wp0[(k + 0) * CC + c], a1 = Wp0[(k + 1) * CC + c];
      const float a2 = Wp0[(k + 2) * CC + c], a3 = Wp0[(k + 3) * CC + c];
      const float b0 = Wp1[(k + 0) * CC + c], b1 = Wp1[(k + 1) * CC + c];
      const float b2 = Wp1[(k + 2) * CC + c], b3 = Wp1[(k + 3) * CC + c];
#pragma unroll
      for (int q = 0; q < 4; ++q) {
        const int nb = p * 4 + q;
        float4 v0 = *(const float4*)&X[nb][0][k];
        acc[q][0] += v0.x * a0 + v0.y * a1 + v0.z * a2 + v0.w * a3;
#pragma unroll
        for (int m = 1; m < 4; ++m) {
          float4 u = *(const float4*)&X[nb][m][k];
          acc[q][m] += u.x * b0 + u.y * b1 + u.z * b2 + u.w * b3;
        }
      }
    }
#pragma unroll
    for (int q = 0; q < 4; ++q)
#pragma unroll
      for (int m = 0; m < 4; ++m) Y[p * 4 + q][m][c] = acc[q][m];
  }
  __syncthreads();
  // ---- stage F: mh / gate / scalars / vec / nf ----
  if (t < 128) {
    const int nb = t >> 4, m = t & 15;
    float acc = 0.f;
    for (int k = 0; k < CC; ++k) acc += Y[nb][0][k] * Wr1[k * 16 + m];
    mh_s[nb][m] = silu_f(acc);
  }
  __syncthreads();
  if (t < 8) {
    float g = 0.f;
#pragma unroll
    for (int m = 0; m < 16; ++m) g += mh_s[t][m] * Wg[m];
    gate_s[t] = silu_f(g);
  }
#pragma unroll
  for (int q = 0; q < 4; ++q) {
    const int nb = p * 4 + q;
    float acc = 0.f;
#pragma unroll
    for (int m = 0; m < 16; ++m) acc += mh_s[nb][m] * Wr2[m * CC + c];
    out_scalars[(size_t)(n0 + nb) * CC + c] = acc;
  }
  __syncthreads();
  if (t < 24) {
    const int nb = t / 3, i = t % 3;
    float acc = 0.f;
    for (int k = 0; k < CC; ++k) acc += Y[nb][1 + i][k] * wv[k];
    out_vec[(size_t)(n0 + nb) * 3 + i] = acc * gate_s[nb];
  }
  for (int i = t; i < 4096; i += 256) out_nf[(size_t)n0 * 512 + i] = Yf[i];
}

extern "C" void kernel_launch(void* const* d_in, const int* in_sizes, int n_in,
                              void* d_out, int out_size, void* d_ws, size_t ws_size,
                              hipStream_t stream) {
  const float* vectors    = (const float*)d_in[0];
  const float* lengths    = (const float*)d_in[1];
  const float* node_feats = (const float*)d_in[2];
  const float* node_attrs = (const float*)d_in[3];
  const float* edge_feats = (const float*)d_in[4];
  const int*   edge_index = (const int*)d_in[5];
  const float* W_up       = (const float*)d_in[6];
  const float* radial_w1  = (const float*)d_in[7];
  const float* radial_b1  = (const float*)d_in[8];
  const float* radial_w2  = (const float*)d_in[9];
  const float* Wd0        = (const float*)d_in[10];
  const float* Wd1        = (const float*)d_in[11];
  const float* Wprod0     = (const float*)d_in[12];
  const float* Wprod1     = (const float*)d_in[13];
  const float* Wp0        = (const float*)d_in[14];
  const float* Wp1        = (const float*)d_in[15];
  const float* Wr1        = (const float*)d_in[16];
  const float* Wr2        = (const float*)d_in[17];
  const float* Wg         = (const float*)d_in[18];
  const float* wv         = (const float*)d_in[19];

  float* out = (float*)d_out;
  float* out_scalars = out;
  float* out_vec = out + (size_t)NN * CC;
  float* out_nf = out + (size_t)NN * CC + (size_t)NN * 3;
  float* sbuf = out_nf;  // reuse the nf output region (N*512 floats) as s-scratch

  // ws layout (~11.7 MB): hbuf | cnt(=cur) | offs | ord | w2h | w2l
  float* hbuf = (float*)d_ws;                       // NN*CC floats
  int* cnt = (int*)(hbuf + (size_t)NN * CC);        // NN (aliased as cur after scan)
  int* offs = cnt + NN;                             // NN+1
  int* ord = offs + NN + 1;                         // NE
  unsigned short* w2h = (unsigned short*)(ord + NE);  // 16384
  unsigned short* w2l = w2h + 16384;                  // 16384

  const int* senders = edge_index;
  const int* receivers = edge_index + NE;

  hipMemsetAsync(cnt, 0, NN * sizeof(int), stream);
  k_prep_w2<<<64, 256, 0, stream>>>(radial_w2, w2h, w2l);
  k_node_h<<<NN / 8, 128, 0, stream>>>(node_feats, W_up, hbuf);
  k_hist<<<NE / 256, 256, 0, stream>>>(receivers, cnt);
  k_scan2<<<1, 1024, 0, stream>>>(cnt, offs);
  k_fill<<<NE / 256, 256, 0, stream>>>(receivers, cnt, ord);
  k_edge_dense<<<NWIN, 256, 0, stream>>>(vectors, lengths, edge_feats, senders,
                                         hbuf, radial_w1, radial_b1, w2h, w2l,
                                         offs, ord, sbuf);
  k_down<<<NN / 8, 256, 0, stream>>>(sbuf, node_attrs, Wd0, Wd1, Wprod0, Wprod1,
                                     Wp0, Wp1, Wr1, Wr2, Wg, wv,
                                     out_scalars, out_vec, out_nf);
}

// Round 4
// 658.114 us; speedup vs baseline: 1.0260x; 1.0260x over previous
//
#include <hip/hip_runtime.h>

#define NN 20000
#define NE 320000
#define CC 128
#define SS 10

typedef __attribute__((ext_vector_type(8))) short short8;
typedef __attribute__((ext_vector_type(4))) float f32x4;

#define MFMA16(a, b, c) __builtin_amdgcn_mfma_f32_16x16x32_bf16(a, b, c, 0, 0, 0)

__device__ __forceinline__ float silu_f(float x) { return x / (1.f + __expf(-x)); }

__device__ __forceinline__ unsigned short f2bf(float x) {  // RNE float->bf16 bits
  unsigned u = __float_as_uint(x);
  unsigned r = u + 0x7FFFu + ((u >> 16) & 1u);
  return (unsigned short)(r >> 16);
}
__device__ __forceinline__ float bf2f(unsigned short h) {
  return __uint_as_float(((unsigned)h) << 16);
}

// ---------------- prep: W2 -> transposed bf16 hi/lo [col][k] ----------------
__global__ __launch_bounds__(256) void k_prep_w2(const float* __restrict__ W2,
                                                 unsigned short* __restrict__ w2h,
                                                 unsigned short* __restrict__ w2l) {
  const int i = blockIdx.x * 256 + threadIdx.x;  // grid 64 -> 16384
  if (i < 64 * 256) {
    const int col = i % 256, k = i / 256;  // i == k*256+col
    const float x = W2[i];
    const unsigned short h = f2bf(x);
    w2h[col * 64 + k] = h;
    w2l[col * 64 + k] = f2bf(x - bf2f(h));
  }
}

// ---------------- h = node_feats @ W_up, 8 nodes per 128-thread block ----------------
__global__ __launch_bounds__(128) void k_node_h(const float* __restrict__ nf,
                                                const float* __restrict__ W,
                                                float* __restrict__ h) {
  __shared__ __align__(16) float rows[8][CC];
  const int c = threadIdx.x;
  const int n0 = blockIdx.x * 8;
#pragma unroll
  for (int q = 0; q < 8; ++q) rows[q][c] = nf[(n0 + q) * CC + c];
  __syncthreads();
  float acc[8] = {0.f, 0.f, 0.f, 0.f, 0.f, 0.f, 0.f, 0.f};
  for (int k = 0; k < CC; k += 4) {
    const float w0 = W[(k + 0) * CC + c];
    const float w1 = W[(k + 1) * CC + c];
    const float w2 = W[(k + 2) * CC + c];
    const float w3 = W[(k + 3) * CC + c];
#pragma unroll
    for (int q = 0; q < 8; ++q) {
      float4 v = *(const float4*)&rows[q][k];
      acc[q] += v.x * w0 + v.y * w1 + v.z * w2 + v.w * w3;
    }
  }
#pragma unroll
  for (int q = 0; q < 8; ++q) h[(n0 + q) * CC + c] = acc[q];
}

// ---------------- CSR build ----------------
__global__ void k_hist(const int* __restrict__ recv, int* __restrict__ cnt) {
  int i = blockIdx.x * blockDim.x + threadIdx.x;
  if (i < NE) atomicAdd(&cnt[recv[i]], 1);
}

// Single block, 1024 threads; each thread scans 20 contiguous counts.
// cntcur is read as counts and overwritten in place with the exclusive prefix.
__global__ __launch_bounds__(1024) void k_scan2(int* cntcur, int* offs) {
  const int t = threadIdx.x;
  int v[20];
  int tot = 0;
  if (t < 1000) {
#pragma unroll
    for (int i = 0; i < 20; ++i) {
      v[i] = cntcur[t * 20 + i];
      tot += v[i];
    }
  }
  const int lane = t & 63;
  int x = tot;
#pragma unroll
  for (int off = 1; off < 64; off <<= 1) {
    int y = __shfl_up(x, off, 64);
    if (lane >= off) x += y;
  }
  __shared__ int wt[16], wo[16];
  if (lane == 63) wt[t >> 6] = x;
  __syncthreads();
  if (t == 0) {
    int a = 0;
    for (int w = 0; w < 16; ++w) {
      wo[w] = a;
      a += wt[w];
    }
    offs[NN] = a;
  }
  __syncthreads();
  int run = wo[t >> 6] + x - tot;
  if (t < 1000) {
#pragma unroll
    for (int i = 0; i < 20; ++i) {
      offs[t * 20 + i] = run;
      cntcur[t * 20 + i] = run;
      run += v[i];
    }
  }
}

// Scatter edges into receiver-sorted order, materializing per-edge records:
// edata[pos][8] = { y1x, y1y, y1z, length, sender(int), eid(int), 0, 0 }
__global__ void k_fill2(const int* __restrict__ recv, const int* __restrict__ snd,
                        const float* __restrict__ vectors,
                        const float* __restrict__ lengths, int* __restrict__ cur,
                        float* __restrict__ edata) {
  int i = blockIdx.x * blockDim.x + threadIdx.x;
  if (i < NE) {
    const int r = recv[i];
    const int pos = atomicAdd(&cur[r], 1);
    const float vx = vectors[i * 3 + 0];
    const float vy = vectors[i * 3 + 1];
    const float vz = vectors[i * 3 + 2];
    const float nr = sqrtf(vx * vx + vy * vy + vz * vz) + 1e-9f;
    const float sc = 1.7320508075688772f / nr;
    float4 a = {vx * sc, vy * sc, vz * sc, lengths[i]};
    *(float4*)&edata[(size_t)pos * 8] = a;
    int2 b = {snd[i], i};
    *(int2*)((char*)edata + (size_t)pos * 32 + 16) = b;
  }
}

// ---------------- wave-autonomous edge aggregation ----------------
// Block = 4 waves; waves share a node stream (grid-stride) but are fully
// independent: wave wv owns a 64-col slice (waves 0,1 -> w0 cols 0..63/64..127;
// waves 2,3 -> w1 same cols). Per 16-edge chunk each wave computes hid for its
// 16 edges DIRECTLY into A-fragments in registers (lane (lm,lg) computes
// hid[lm][k], k = s*32+lg*8+j — exactly the A layout; k-formula matches the
// B side so any shared k-permutation cancels). B-frags (W2 bf16 hi/lo) live in
// 64 VGPRs. Segment accumulation in registers; shfl-reduce once per node.
// NO __syncthreads in the main loop (only once after W1/B1 LDS init).
__global__ __launch_bounds__(256) void k_edge_wave(
    const float* __restrict__ efeat, const float* __restrict__ hbuf,
    const float* __restrict__ W1, const float* __restrict__ B1,
    const unsigned short* __restrict__ w2h, const unsigned short* __restrict__ w2l,
    const int* __restrict__ offs, const float* __restrict__ edata,
    float* __restrict__ sout) {
  __shared__ __align__(16) float W1s[9 * 64];
  __shared__ __align__(16) float B1s[64];
  const int t = threadIdx.x;
  const int l = t & 63, wv = t >> 6, lg = l >> 4, lm = l & 15;
  const int half = wv & 1;
  const bool isw1 = wv >= 2;

  for (int i = t; i < 576; i += 256) W1s[i] = W1[i];
  if (t < 64) B1s[t] = B1[t];

  // B-frags: col = 128*isw1 + half*64 + ct*16 + lm ; k = s*32 + lg*8 + j
  short8 Bh[4][2], Bl[4][2];
#pragma unroll
  for (int ct = 0; ct < 4; ++ct)
#pragma unroll
    for (int s = 0; s < 2; ++s) {
      const int col = (isw1 ? 128 : 0) + half * 64 + ct * 16 + lm;
      Bh[ct][s] = *(const short8*)&w2h[col * 64 + s * 32 + lg * 8];
      Bl[ct][s] = *(const short8*)&w2l[col * 64 + s * 32 + lg * 8];
    }
  __syncthreads();  // W1s/B1s ready (only barrier; hit exactly once)

  const float inv = 1.f / 16.f;
  for (int n = blockIdx.x; n < NN; n += gridDim.x) {
    const int beg = offs[n], endo = offs[n + 1];
    float p0[4] = {0.f, 0.f, 0.f, 0.f};
    float px[4] = {0.f, 0.f, 0.f, 0.f};
    float py[4] = {0.f, 0.f, 0.f, 0.f};
    float pz[4] = {0.f, 0.f, 0.f, 0.f};
    for (int cb = beg; cb < endo; cb += 16) {
      const int cnt = min(16, endo - cb);
      // --- hid-role inputs (longest chain: issue first) ---
      const int posm = cb + lm;
      const bool livem = lm < cnt;
      float4 e0 = {0.f, 0.f, 0.f, 0.f}, e1 = {0.f, 0.f, 0.f, 0.f};
      float lenm = 0.f;
      if (livem) {
        lenm = edata[(size_t)posm * 8 + 3];
        const int eidm = ((const int*)edata)[(size_t)posm * 8 + 5];
        e0 = *(const float4*)&efeat[(size_t)eidm * 8];
        e1 = *(const float4*)&efeat[(size_t)eidm * 8 + 4];
      }
      // --- consume-role inputs ---
      int sd[4];
      float y1a[4], y1b[4], y1c[4];
#pragma unroll
      for (int r = 0; r < 4; ++r) {
        const int er = lg * 4 + r;
        const int pos = cb + er;
        float4 yl = {0.f, 0.f, 0.f, 0.f};
        int2 se = {0, 0};
        if (er < cnt) {
          yl = *(const float4*)&edata[(size_t)pos * 8];
          se = *(const int2*)((const char*)edata + (size_t)pos * 32 + 16);
        }
        sd[r] = se.x;
        y1a[r] = yl.x;
        y1b[r] = yl.y;
        y1c[r] = yl.z;
      }
      float hc[4][4];
#pragma unroll
      for (int ct = 0; ct < 4; ++ct) {
        const int col = half * 64 + ct * 16 + lm;
#pragma unroll
        for (int r = 0; r < 4; ++r) hc[ct][r] = hbuf[(size_t)sd[r] * CC + col];
      }
      // --- hid -> A-fragments (in registers, no LDS round trip) ---
      float ef[9];
      ef[0] = e0.x; ef[1] = e0.y; ef[2] = e0.z; ef[3] = e0.w;
      ef[4] = e1.x; ef[5] = e1.y; ef[6] = e1.z; ef[7] = e1.w;
      ef[8] = lenm;
      short8 Ah[2], Al[2];
#pragma unroll
      for (int s = 0; s < 2; ++s) {
        const int k0 = s * 32 + lg * 8;
        float4 xa = *(const float4*)&B1s[k0];
        float4 xb = *(const float4*)&B1s[k0 + 4];
#pragma unroll
        for (int r = 0; r < 9; ++r) {
          const float4 wa = *(const float4*)&W1s[r * 64 + k0];
          const float4 wb = *(const float4*)&W1s[r * 64 + k0 + 4];
          xa.x += ef[r] * wa.x; xa.y += ef[r] * wa.y;
          xa.z += ef[r] * wa.z; xa.w += ef[r] * wa.w;
          xb.x += ef[r] * wb.x; xb.y += ef[r] * wb.y;
          xb.z += ef[r] * wb.z; xb.w += ef[r] * wb.w;
        }
        float xs0 = livem ? silu_f(xa.x) : 0.f;
        float xs1 = livem ? silu_f(xa.y) : 0.f;
        float xs2 = livem ? silu_f(xa.z) : 0.f;
        float xs3 = livem ? silu_f(xa.w) : 0.f;
        float xs4 = livem ? silu_f(xb.x) : 0.f;
        float xs5 = livem ? silu_f(xb.y) : 0.f;
        float xs6 = livem ? silu_f(xb.z) : 0.f;
        float xs7 = livem ? silu_f(xb.w) : 0.f;
        unsigned short h0 = f2bf(xs0), h1 = f2bf(xs1), h2 = f2bf(xs2), h3 = f2bf(xs3);
        unsigned short h4 = f2bf(xs4), h5 = f2bf(xs5), h6 = f2bf(xs6), h7 = f2bf(xs7);
        short8 ah, al;
        ah[0] = (short)h0; ah[1] = (short)h1; ah[2] = (short)h2; ah[3] = (short)h3;
        ah[4] = (short)h4; ah[5] = (short)h5; ah[6] = (short)h6; ah[7] = (short)h7;
        al[0] = (short)f2bf(xs0 - bf2f(h0)); al[1] = (short)f2bf(xs1 - bf2f(h1));
        al[2] = (short)f2bf(xs2 - bf2f(h2)); al[3] = (short)f2bf(xs3 - bf2f(h3));
        al[4] = (short)f2bf(xs4 - bf2f(h4)); al[5] = (short)f2bf(xs5 - bf2f(h5));
        al[6] = (short)f2bf(xs6 - bf2f(h6)); al[7] = (short)f2bf(xs7 - bf2f(h7));
        Ah[s] = ah;
        Al[s] = al;
      }
      // --- MFMA + consume (wave-uniform branch) ---
      if (!isw1) {
#pragma unroll
        for (int ct = 0; ct < 4; ++ct) {
          f32x4 acc = {0.f, 0.f, 0.f, 0.f};
          acc = MFMA16(Ah[0], Bh[ct][0], acc);
          acc = MFMA16(Ah[0], Bl[ct][0], acc);
          acc = MFMA16(Al[0], Bh[ct][0], acc);
          acc = MFMA16(Ah[1], Bh[ct][1], acc);
          acc = MFMA16(Ah[1], Bl[ct][1], acc);
          acc = MFMA16(Al[1], Bh[ct][1], acc);
          p0[ct] += acc[0] * hc[ct][0] + acc[1] * hc[ct][1] +
                    acc[2] * hc[ct][2] + acc[3] * hc[ct][3];
        }
      } else {
#pragma unroll
        for (int ct = 0; ct < 4; ++ct) {
          f32x4 acc = {0.f, 0.f, 0.f, 0.f};
          acc = MFMA16(Ah[0], Bh[ct][0], acc);
          acc = MFMA16(Ah[0], Bl[ct][0], acc);
          acc = MFMA16(Al[0], Bh[ct][0], acc);
          acc = MFMA16(Ah[1], Bh[ct][1], acc);
          acc = MFMA16(Ah[1], Bl[ct][1], acc);
          acc = MFMA16(Al[1], Bh[ct][1], acc);
#pragma unroll
          for (int r = 0; r < 4; ++r) {
            const float m = acc[r] * hc[ct][r];
            px[ct] += m * y1a[r];
            py[ct] += m * y1b[r];
            pz[ct] += m * y1c[r];
          }
        }
      }
    }  // chunk loop
    // reduce over lane groups (l, l^16, l^32, l^48 share a column) + write
    if (!isw1) {
#pragma unroll
      for (int ct = 0; ct < 4; ++ct) {
        float v = p0[ct];
        v += __shfl_xor(v, 16, 64);
        v += __shfl_xor(v, 32, 64);
        if (lg == 0) sout[(size_t)n * 512 + half * 64 + ct * 16 + lm] = v * inv;
      }
    } else {
#pragma unroll
      for (int ct = 0; ct < 4; ++ct) {
        float vx = px[ct], vy = py[ct], vz = pz[ct];
        vx += __shfl_xor(vx, 16, 64); vx += __shfl_xor(vx, 32, 64);
        vy += __shfl_xor(vy, 16, 64); vy += __shfl_xor(vy, 32, 64);
        vz += __shfl_xor(vz, 16, 64); vz += __shfl_xor(vz, 32, 64);
        if (lg == 0) {
          const int c = half * 64 + ct * 16 + lm;
          sout[(size_t)n * 512 + 128 + c] = vx * inv;
          sout[(size_t)n * 512 + 256 + c] = vy * inv;
          sout[(size_t)n * 512 + 384 + c] = vz * inv;
        }
      }
    }
  }  // node loop
}

// ---------------- fused downstream: 8 nodes per 256-thread block ----------------
__global__ __launch_bounds__(256) void k_down(
    const float* __restrict__ sbuf, const float* __restrict__ attrs,
    const float* __restrict__ Wd0, const float* __restrict__ Wd1,
    const float* __restrict__ Wprod0, const float* __restrict__ Wprod1,
    const float* __restrict__ Wp0, const float* __restrict__ Wp1,
    const float* __restrict__ Wr1, const float* __restrict__ Wr2,
    const float* __restrict__ Wg, const float* __restrict__ wv,
    float* __restrict__ out_scalars, float* __restrict__ out_vec,
    float* __restrict__ out_nf) {
  __shared__ __align__(16) float X[8][4][CC];  // s, then b
  __shared__ __align__(16) float Y[8][4][CC];  // a, then h
  __shared__ float at_s[8][SS];
  __shared__ float mh_s[8][16];
  __shared__ float gate_s[8];
  const int t = threadIdx.x;
  const int c = t & 127, p = t >> 7;
  const int n0 = blockIdx.x * 8;
  float* Xf = &X[0][0][0];
  float* Yf = &Y[0][0][0];
  for (int i = t; i < 4096; i += 256) Xf[i] = sbuf[(size_t)n0 * 512 + i];
  for (int i = t; i < 8 * SS; i += 256) at_s[i / SS][i % SS] = attrs[n0 * SS + i];
  __syncthreads();
  // ---- stage A: a = s @ [Wd0 | Wd1] ----
  {
    float acc[4][4];
#pragma unroll
    for (int q = 0; q < 4; ++q)
#pragma unroll
      for (int m = 0; m < 4; ++m) acc[q][m] = 0.f;
    for (int k = 0; k < CC; k += 4) {
      const float a0 = Wd0[(k + 0) * CC + c], a1 = Wd0[(k + 1) * CC + c];
      const float a2 = Wd0[(k + 2) * CC + c], a3 = Wd0[(k + 3) * CC + c];
      const float b0 = Wd1[(k + 0) * CC + c], b1 = Wd1[(k + 1) * CC + c];
      const float b2 = Wd1[(k + 2) * CC + c], b3 = Wd1[(k + 3) * CC + c];
#pragma unroll
      for (int q = 0; q < 4; ++q) {
        const int nb = p * 4 + q;
        float4 v0 = *(const float4*)&X[nb][0][k];
        acc[q][0] += v0.x * a0 + v0.y * a1 + v0.z * a2 + v0.w * a3;
#pragma unroll
        for (int m = 1; m < 4; ++m) {
          float4 u = *(const float4*)&X[nb][m][k];
          acc[q][m] += u.x * b0 + u.y * b1 + u.z * b2 + u.w * b3;
        }
      }
    }
#pragma unroll
    for (int q = 0; q < 4; ++q)
#pragma unroll
      for (int m = 0; m < 4; ++m) Y[p * 4 + q][m][c] = acc[q][m];
  }
  __syncthreads();
  // ---- stage B: pointwise paths / species product (X := b) ----
#pragma unroll
  for (int q = 0; q < 4; ++q) {
    const int nb = p * 4 + q;
    const float a0 = Y[nb][0][c];
    const float ax = Y[nb][1][c], ay = Y[nb][2][c], az = Y[nb][3][c];
    const float dot = ax * ax + ay * ay + az * az;
    int sidx = 0;
#pragma unroll
    for (int si = 0; si < SS; ++si)
      if (at_s[nb][si] > 0.5f) sidx = si;
    const float a0sq = a0 * a0;
    const float b0v = Wprod0[(sidx * 5 + 0) * CC + c] * a0 +
                      Wprod0[(sidx * 5 + 1) * CC + c] * a0sq +
                      Wprod0[(sidx * 5 + 2) * CC + c] * dot +
                      Wprod0[(sidx * 5 + 3) * CC + c] * (a0sq * a0) +
                      Wprod0[(sidx * 5 + 4) * CC + c] * (a0 * dot);
    const float fac = Wprod1[(sidx * 4 + 0) * CC + c] +
                      Wprod1[(sidx * 4 + 1) * CC + c] * a0 +
                      Wprod1[(sidx * 4 + 2) * CC + c] * a0sq +
                      Wprod1[(sidx * 4 + 3) * CC + c] * dot;
    X[nb][0][c] = b0v;
    X[nb][1][c] = ax * fac;
    X[nb][2][c] = ay * fac;
    X[nb][3][c] = az * fac;
  }
  __syncthreads();
  // ---- stage H: h = b @ [Wp0 | Wp1] (Y := h) ----
  {
    float acc[4][4];
#pragma unroll
    for (int q = 0; q < 4; ++q)
#pragma unroll
      for (int m = 0; m < 4; ++m) acc[q][m] = 0.f;
    for (int k = 0; k < CC; k += 4) {
      const float a0 = Wp0[(k + 0) * CC + c], a1 = Wp0[(k + 1) * CC + c];
      const float a2 = Wp0[(k + 2) * CC + c], a3 = Wp0[(k + 3) * CC + c];
      const float b0 = Wp1[(k + 0) * CC + c], b1 = Wp1[(k + 1) * CC + c];
      const float b2 = Wp1[(k + 2) * CC + c], b3 = Wp1[(k + 3) * CC + c];
#pragma unroll
      for (int q = 0; q < 4; ++q) {
        const int nb = p * 4 + q;
        float4 v0 = *(const float4*)&X[nb][0][k];
        acc[q][0] += v0.x * a0 + v0.y * a1 + v0.z * a2 + v0.w * a3;
#pragma unroll
        for (int m = 1; m < 4; ++m) {
          float4 u = *(const float4*)&X[nb][m][k];
          acc[q][m] += u.x * b0 + u.y * b1 + u.z * b2 + u.w * b3;
        }
      }
    }
#pragma unroll
    for (int q = 0; q < 4; ++q)
#pragma unroll
      for (int m = 0; m < 4; ++m) Y[p * 4 + q][m][c] = acc[q][m];
  }
  __syncthreads();
  // ---- stage F: mh / gate / scalars / vec / nf ----
  if (t < 128) {
    const int nb = t >> 4, m = t & 15;
    float acc = 0.f;
    for (int k = 0; k < CC; ++k) acc += Y[nb][0][k] * Wr1[k * 16 + m];
    mh_s[nb][m] = silu_f(acc);
  }
  __syncthreads();
  if (t < 8) {
    float g = 0.f;
#pragma unroll
    for (int m = 0; m < 16; ++m) g += mh_s[t][m] * Wg[m];
    gate_s[t] = silu_f(g);
  }
#pragma unroll
  for (int q = 0; q < 4; ++q) {
    const int nb = p * 4 + q;
    float acc = 0.f;
#pragma unroll
    for (int m = 0; m < 16; ++m) acc += mh_s[nb][m] * Wr2[m * CC + c];
    out_scalars[(size_t)(n0 + nb) * CC + c] = acc;
  }
  __syncthreads();
  if (t < 24) {
    const int nb = t / 3, i = t % 3;
    float acc = 0.f;
    for (int k = 0; k < CC; ++k) acc += Y[nb][1 + i][k] * wv[k];
    out_vec[(size_t)(n0 + nb) * 3 + i] = acc * gate_s[nb];
  }
  for (int i = t; i < 4096; i += 256) out_nf[(size_t)n0 * 512 + i] = Yf[i];
}

extern "C" void kernel_launch(void* const* d_in, const int* in_sizes, int n_in,
                              void* d_out, int out_size, void* d_ws, size_t ws_size,
                              hipStream_t stream) {
  const float* vectors    = (const float*)d_in[0];
  const float* lengths    = (const float*)d_in[1];
  const float* node_feats = (const float*)d_in[2];
  const float* node_attrs = (const float*)d_in[3];
  const float* edge_feats = (const float*)d_in[4];
  const int*   edge_index = (const int*)d_in[5];
  const float* W_up       = (const float*)d_in[6];
  const float* radial_w1  = (const float*)d_in[7];
  const float* radial_b1  = (const float*)d_in[8];
  const float* radial_w2  = (const float*)d_in[9];
  const float* Wd0        = (const float*)d_in[10];
  const float* Wd1        = (const float*)d_in[11];
  const float* Wprod0     = (const float*)d_in[12];
  const float* Wprod1     = (const float*)d_in[13];
  const float* Wp0        = (const float*)d_in[14];
  const float* Wp1        = (const float*)d_in[15];
  const float* Wr1        = (const float*)d_in[16];
  const float* Wr2        = (const float*)d_in[17];
  const float* Wg         = (const float*)d_in[18];
  const float* wv         = (const float*)d_in[19];

  float* out = (float*)d_out;
  float* out_scalars = out;
  float* out_vec = out + (size_t)NN * CC;
  float* out_nf = out + (size_t)NN * CC + (size_t)NN * 3;
  float* sbuf = out_nf;  // reuse the nf output region (N*512 floats) as s-scratch

  // ws layout (~20.8 MB): hbuf | cnt(=cur) | offs(+pad) | edata | w2h | w2l
  float* hbuf = (float*)d_ws;                         // NN*CC floats
  int* cnt = (int*)(hbuf + (size_t)NN * CC);          // NN (aliased as cur)
  int* offs = cnt + NN;                               // NN+4 (padded for align)
  float* edata = (float*)(offs + NN + 4);             // NE*8 floats (32B records)
  unsigned short* w2h = (unsigned short*)(edata + (size_t)NE * 8);  // 16384
  unsigned short* w2l = w2h + 16384;                                // 16384

  const int* senders = edge_index;
  const int* receivers = edge_index + NE;

  hipMemsetAsync(cnt, 0, NN * sizeof(int), stream);
  k_prep_w2<<<64, 256, 0, stream>>>(radial_w2, w2h, w2l);
  k_node_h<<<NN / 8, 128, 0, stream>>>(node_feats, W_up, hbuf);
  k_hist<<<NE / 256, 256, 0, stream>>>(receivers, cnt);
  k_scan2<<<1, 1024, 0, stream>>>(cnt, offs);
  k_fill2<<<NE / 256, 256, 0, stream>>>(receivers, senders, vectors, lengths,
                                        cnt, edata);
  k_edge_wave<<<2048, 256, 0, stream>>>(edge_feats, hbuf, radial_w1, radial_b1,
                                        w2h, w2l, offs, edata, sbuf);
  k_down<<<NN / 8, 256, 0, stream>>>(sbuf, node_attrs, Wd0, Wd1, Wprod0, Wprod1,
                                     Wp0, Wp1, Wr1, Wr2, Wg, wv,
                                     out_scalars, out_vec, out_nf);
}

// Round 5
// 433.224 us; speedup vs baseline: 1.5586x; 1.5191x over previous
//
#include <hip/hip_runtime.h>

#define NN 20000
#define NE 320000
#define CC 128
#define SS 10
#define NWIN 10000  // 2 nodes per window

typedef __attribute__((ext_vector_type(8))) short short8;
typedef __attribute__((ext_vector_type(4))) float f32x4;

#define MFMA16(a, b, c) __builtin_amdgcn_mfma_f32_16x16x32_bf16(a, b, c, 0, 0, 0)

__device__ __forceinline__ float silu_f(float x) { return x / (1.f + __expf(-x)); }

__device__ __forceinline__ unsigned short f2bf(float x) {  // RNE float->bf16 bits
  unsigned u = __float_as_uint(x);
  unsigned r = u + 0x7FFFu + ((u >> 16) & 1u);
  return (unsigned short)(r >> 16);
}
__device__ __forceinline__ float bf2f(unsigned short h) {
  return __uint_as_float(((unsigned)h) << 16);
}

// ---------------- prep: W2 -> transposed bf16 hi/lo [col][k] ----------------
__global__ __launch_bounds__(256) void k_prep_w2(const float* __restrict__ W2,
                                                 unsigned short* __restrict__ w2h,
                                                 unsigned short* __restrict__ w2l) {
  const int i = blockIdx.x * 256 + threadIdx.x;  // grid 64 -> 16384
  if (i < 64 * 256) {
    const int col = i % 256, k = i / 256;  // i == k*256+col
    const float x = W2[i];
    const unsigned short h = f2bf(x);
    w2h[col * 64 + k] = h;
    w2l[col * 64 + k] = f2bf(x - bf2f(h));
  }
}

// ---------------- h = node_feats @ W_up, 8 nodes per 128-thread block ----------------
__global__ __launch_bounds__(128) void k_node_h(const float* __restrict__ nf,
                                                const float* __restrict__ W,
                                                float* __restrict__ h) {
  __shared__ __align__(16) float rows[8][CC];
  const int c = threadIdx.x;
  const int n0 = blockIdx.x * 8;
#pragma unroll
  for (int q = 0; q < 8; ++q) rows[q][c] = nf[(n0 + q) * CC + c];
  __syncthreads();
  float acc[8] = {0.f, 0.f, 0.f, 0.f, 0.f, 0.f, 0.f, 0.f};
  for (int k = 0; k < CC; k += 4) {
    const float w0 = W[(k + 0) * CC + c];
    const float w1 = W[(k + 1) * CC + c];
    const float w2 = W[(k + 2) * CC + c];
    const float w3 = W[(k + 3) * CC + c];
#pragma unroll
    for (int q = 0; q < 8; ++q) {
      float4 v = *(const float4*)&rows[q][k];
      acc[q] += v.x * w0 + v.y * w1 + v.z * w2 + v.w * w3;
    }
  }
#pragma unroll
  for (int q = 0; q < 8; ++q) h[(n0 + q) * CC + c] = acc[q];
}

// ---------------- CSR build ----------------
__global__ void k_hist(const int* __restrict__ recv, int* __restrict__ cnt) {
  int i = blockIdx.x * blockDim.x + threadIdx.x;
  if (i < NE) atomicAdd(&cnt[recv[i]], 1);
}

// Single block, 1024 threads; each thread scans 20 contiguous counts.
__global__ __launch_bounds__(1024) void k_scan2(int* cntcur, int* offs) {
  const int t = threadIdx.x;
  int v[20];
  int tot = 0;
  if (t < 1000) {
#pragma unroll
    for (int i = 0; i < 20; ++i) {
      v[i] = cntcur[t * 20 + i];
      tot += v[i];
    }
  }
  const int lane = t & 63;
  int x = tot;
#pragma unroll
  for (int off = 1; off < 64; off <<= 1) {
    int y = __shfl_up(x, off, 64);
    if (lane >= off) x += y;
  }
  __shared__ int wt[16], wo[16];
  if (lane == 63) wt[t >> 6] = x;
  __syncthreads();
  if (t == 0) {
    int a = 0;
    for (int w = 0; w < 16; ++w) {
      wo[w] = a;
      a += wt[w];
    }
    offs[NN] = a;
  }
  __syncthreads();
  int run = wo[t >> 6] + x - tot;
  if (t < 1000) {
#pragma unroll
    for (int i = 0; i < 20; ++i) {
      offs[t * 20 + i] = run;
      cntcur[t * 20 + i] = run;
      run += v[i];
    }
  }
}

// Scatter edges into receiver-sorted 64B records:
// rec[0..2]=y1*sqrt3, rec[3]=len, rec[4..11]=efeat, int(rec[12])=sender
__global__ void k_fill2(const int* __restrict__ recv, const int* __restrict__ snd,
                        const float* __restrict__ vectors,
                        const float* __restrict__ lengths,
                        const float* __restrict__ efeat, int* __restrict__ cur,
                        float* __restrict__ edata) {
  int i = blockIdx.x * blockDim.x + threadIdx.x;
  if (i < NE) {
    const int r = recv[i];
    const int pos = atomicAdd(&cur[r], 1);
    const float vx = vectors[i * 3 + 0];
    const float vy = vectors[i * 3 + 1];
    const float vz = vectors[i * 3 + 2];
    const float nr = sqrtf(vx * vx + vy * vy + vz * vz) + 1e-9f;
    const float sc = 1.7320508075688772f / nr;
    float4 a = {vx * sc, vy * sc, vz * sc, lengths[i]};
    float4 b = *(const float4*)&efeat[(size_t)i * 8];
    float4 c = *(const float4*)&efeat[(size_t)i * 8 + 4];
    float4 d;
    ((int*)&d)[0] = snd[i];
    d.y = 0.f; d.z = 0.f; d.w = 0.f;
    float* rec = edata + (size_t)pos * 16;
    *(float4*)rec = a;
    *(float4*)(rec + 4) = b;
    *(float4*)(rec + 8) = c;
    *(float4*)(rec + 12) = d;
  }
}

// ---------------- dense 2-node-window edge aggregation ----------------
// Block = 4 waves, one window of 2 consecutive nodes. Per 32-edge pass:
//   stage (1 coalesced float4/thread) -> barrier -> hid once (256 threads,
//   bf16 hi/lo packed to LDS) -> barrier -> 2x 16-row subtiles: full MFMA
//   (wave wv owns w-cols [wv*64,wv*64+64)), gather h[sender], vv=acc*hc,
//   node-range-PREDICATED accumulation into per-slot registers.
// Flush: shfl-reduce per slot, plain stores. 3 barriers per 32 edges.
__global__ __launch_bounds__(256) void k_edge2(
    const float* __restrict__ hbuf, const float* __restrict__ W1,
    const float* __restrict__ B1, const unsigned short* __restrict__ w2h,
    const unsigned short* __restrict__ w2l, const int* __restrict__ offs,
    const float* __restrict__ edata, float* __restrict__ sout) {
  __shared__ __align__(16) float W1s[9 * 64];
  __shared__ __align__(16) float B1s[64];
  __shared__ __align__(16) float ed[32][16];
  __shared__ __align__(16) unsigned short hidh[32][72];
  __shared__ __align__(16) unsigned short hidl[32][72];

  const int t = threadIdx.x;
  const int l = t & 63, wv = t >> 6, lg = l >> 4, lm = l & 15;
  const int half = wv & 1;
  const bool isw1 = wv >= 2;

  for (int i = t; i < 576; i += 256) W1s[i] = W1[i];
  if (t < 64) B1s[t] = B1[t];

  // B-frags: wave wv owns w-cols [wv*64, wv*64+64): col = wv*64+ct*16+lm,
  // k = s*32+lg*8+j (same formula as the A side -> shared perms cancel).
  short8 Bh[4][2], Bl[4][2];
#pragma unroll
  for (int ct = 0; ct < 4; ++ct)
#pragma unroll
    for (int s = 0; s < 2; ++s) {
      const int col = wv * 64 + ct * 16 + lm;
      Bh[ct][s] = *(const short8*)&w2h[col * 64 + s * 32 + lg * 8];
      Bl[ct][s] = *(const short8*)&w2l[col * 64 + s * 32 + lg * 8];
    }

  const int nb = blockIdx.x * 2;
  const int o0 = offs[nb], o1 = offs[nb + 1], o2 = offs[nb + 2];

  float p0[2][4] = {};
  float px[2][4] = {}, py[2][4] = {}, pz[2][4] = {};

  const int npass = (o2 - o0 + 31) >> 5;
  for (int p = 0; p < npass; ++p) {
    const int base = o0 + p * 32;
    const int cnt = min(32, o2 - base);
    __syncthreads();  // LDS reuse guard (also covers W1s init on first pass)
    if (t < 128) {  // stage: 32 records x 4 float4, fully coalesced
      const int e = t >> 2, q = t & 3;
      float4 v = {0.f, 0.f, 0.f, 0.f};
      if (e < cnt) v = *(const float4*)&edata[((size_t)(base + e)) * 16 + q * 4];
      *(float4*)&ed[e][q * 4] = v;
    }
    __syncthreads();
    {  // hid once: thread t -> edge e=t&31, k-range [kseg*8, kseg*8+8)
      const int e = t & 31, kseg = t >> 5;
      const int k0 = kseg * 8;
      float ef[9];
#pragma unroll
      for (int r = 0; r < 8; ++r) ef[r] = ed[e][4 + r];
      ef[8] = ed[e][3];
      float4 xa = *(const float4*)&B1s[k0];
      float4 xb = *(const float4*)&B1s[k0 + 4];
#pragma unroll
      for (int r = 0; r < 9; ++r) {
        const float4 wa = *(const float4*)&W1s[r * 64 + k0];
        const float4 wb = *(const float4*)&W1s[r * 64 + k0 + 4];
        xa.x += ef[r] * wa.x; xa.y += ef[r] * wa.y;
        xa.z += ef[r] * wa.z; xa.w += ef[r] * wa.w;
        xb.x += ef[r] * wb.x; xb.y += ef[r] * wb.y;
        xb.z += ef[r] * wb.z; xb.w += ef[r] * wb.w;
      }
      float xs[8];
      xs[0] = silu_f(xa.x); xs[1] = silu_f(xa.y);
      xs[2] = silu_f(xa.z); xs[3] = silu_f(xa.w);
      xs[4] = silu_f(xb.x); xs[5] = silu_f(xb.y);
      xs[6] = silu_f(xb.z); xs[7] = silu_f(xb.w);
      short8 ah, al;
#pragma unroll
      for (int j = 0; j < 8; ++j) {
        const unsigned short h = f2bf(xs[j]);
        ah[j] = (short)h;
        al[j] = (short)f2bf(xs[j] - bf2f(h));
      }
      *(short8*)&hidh[e][k0] = ah;
      *(short8*)&hidl[e][k0] = al;
      // dead edges (e>=cnt): ed zeroed -> hid=silu(B1) finite; masked in consume
    }
    __syncthreads();
#pragma unroll 1
    for (int sc = 0; sc < 2; ++sc) {
      const int gr0 = base + sc * 16;
      if (gr0 >= o2) break;
      short8 Ah0 = *(const short8*)&hidh[sc * 16 + lm][lg * 8];
      short8 Ah1 = *(const short8*)&hidh[sc * 16 + lm][32 + lg * 8];
      short8 Al0 = *(const short8*)&hidl[sc * 16 + lm][lg * 8];
      short8 Al1 = *(const short8*)&hidl[sc * 16 + lm][32 + lg * 8];
      f32x4 acc[4];
#pragma unroll
      for (int ct = 0; ct < 4; ++ct) {
        f32x4 a = {0.f, 0.f, 0.f, 0.f};
        a = MFMA16(Ah0, Bh[ct][0], a);
        a = MFMA16(Ah0, Bl[ct][0], a);
        a = MFMA16(Al0, Bh[ct][0], a);
        a = MFMA16(Ah1, Bh[ct][1], a);
        a = MFMA16(Ah1, Bl[ct][1], a);
        a = MFMA16(Al1, Bh[ct][1], a);
        acc[ct] = a;
      }
      // consume: C/D layout col=lane&15, row=lg*4+reg  [m89/m91-verified]
      const int r0 = sc * 16 + lg * 4;
      int sd[4];
      float y1a[4], y1b[4], y1c[4];
#pragma unroll
      for (int r = 0; r < 4; ++r) {
        sd[r] = __float_as_int(ed[r0 + r][12]);
        y1a[r] = ed[r0 + r][0];
        y1b[r] = ed[r0 + r][1];
        y1c[r] = ed[r0 + r][2];
      }
      float vv[4][4];
#pragma unroll
      for (int ct = 0; ct < 4; ++ct) {
        const int hcol = half * 64 + ct * 16 + lm;
#pragma unroll
        for (int r = 0; r < 4; ++r)
          vv[ct][r] = acc[ct][r] * hbuf[(size_t)sd[r] * CC + hcol];
      }
      const int grow0 = gr0 + lg * 4;
#pragma unroll
      for (int sl = 0; sl < 2; ++sl) {
        const int slo = sl ? o1 : o0;
        const int shi = sl ? o2 : o1;
        if (shi > gr0 && slo < gr0 + 16) {  // wave-uniform intersect test
          if (!isw1) {
#pragma unroll
            for (int r = 0; r < 4; ++r) {
              const bool in = (grow0 + r >= slo) && (grow0 + r < shi);
#pragma unroll
              for (int ct = 0; ct < 4; ++ct)
                p0[sl][ct] += in ? vv[ct][r] : 0.f;
            }
          } else {
#pragma unroll
            for (int r = 0; r < 4; ++r) {
              const bool in = (grow0 + r >= slo) && (grow0 + r < shi);
#pragma unroll
              for (int ct = 0; ct < 4; ++ct) {
                const float m = in ? vv[ct][r] : 0.f;
                px[sl][ct] += m * y1a[r];
                py[sl][ct] += m * y1b[r];
                pz[sl][ct] += m * y1c[r];
              }
            }
          }
        }
      }
    }  // subtiles
  }  // passes
  // flush: reduce over lane groups (l, l^16, l^32, l^48 share a column)
  const float inv = 1.f / 16.f;
#pragma unroll
  for (int sl = 0; sl < 2; ++sl) {
    const int n = nb + sl;
    if (!isw1) {
#pragma unroll
      for (int ct = 0; ct < 4; ++ct) {
        float v = p0[sl][ct];
        v += __shfl_xor(v, 16, 64);
        v += __shfl_xor(v, 32, 64);
        if (lg == 0) sout[(size_t)n * 512 + half * 64 + ct * 16 + lm] = v * inv;
      }
    } else {
#pragma unroll
      for (int ct = 0; ct < 4; ++ct) {
        float vx = px[sl][ct], vy = py[sl][ct], vz = pz[sl][ct];
        vx += __shfl_xor(vx, 16, 64); vx += __shfl_xor(vx, 32, 64);
        vy += __shfl_xor(vy, 16, 64); vy += __shfl_xor(vy, 32, 64);
        vz += __shfl_xor(vz, 16, 64); vz += __shfl_xor(vz, 32, 64);
        if (lg == 0) {
          const int c = half * 64 + ct * 16 + lm;
          sout[(size_t)n * 512 + 128 + c] = vx * inv;
          sout[(size_t)n * 512 + 256 + c] = vy * inv;
          sout[(size_t)n * 512 + 384 + c] = vz * inv;
        }
      }
    }
  }
}

// ---------------- fused downstream: 8 nodes per 256-thread block ----------------
__global__ __launch_bounds__(256) void k_down(
    const float* __restrict__ sbuf, const float* __restrict__ attrs,
    const float* __restrict__ Wd0, const float* __restrict__ Wd1,
    const float* __restrict__ Wprod0, const float* __restrict__ Wprod1,
    const float* __restrict__ Wp0, const float* __restrict__ Wp1,
    const float* __restrict__ Wr1, const float* __restrict__ Wr2,
    const float* __restrict__ Wg, const float* __restrict__ wv,
    float* __restrict__ out_scalars, float* __restrict__ out_vec,
    float* __restrict__ out_nf) {
  __shared__ __align__(16) float X[8][4][CC];  // s, then b
  __shared__ __align__(16) float Y[8][4][CC];  // a, then h
  __shared__ float at_s[8][SS];
  __shared__ float mh_s[8][16];
  __shared__ float gate_s[8];
  const int t = threadIdx.x;
  const int c = t & 127, p = t >> 7;
  const int n0 = blockIdx.x * 8;
  float* Xf = &X[0][0][0];
  float* Yf = &Y[0][0][0];
  for (int i = t; i < 4096; i += 256) Xf[i] = sbuf[(size_t)n0 * 512 + i];
  for (int i = t; i < 8 * SS; i += 256) at_s[i / SS][i % SS] = attrs[n0 * SS + i];
  __syncthreads();
  // ---- stage A: a = s @ [Wd0 | Wd1] ----
  {
    float acc[4][4];
#pragma unroll
    for (int q = 0; q < 4; ++q)
#pragma unroll
      for (int m = 0; m < 4; ++m) acc[q][m] = 0.f;
    for (int k = 0; k < CC; k += 4) {
      const float a0 = Wd0[(k + 0) * CC + c], a1 = Wd0[(k + 1) * CC + c];
      const float a2 = Wd0[(k + 2) * CC + c], a3 = Wd0[(k + 3) * CC + c];
      const float b0 = Wd1[(k + 0) * CC + c], b1 = Wd1[(k + 1) * CC + c];
      const float b2 = Wd1[(k + 2) * CC + c], b3 = Wd1[(k + 3) * CC + c];
#pragma unroll
      for (int q = 0; q < 4; ++q) {
        const int nb = p * 4 + q;
        float4 v0 = *(const float4*)&X[nb][0][k];
        acc[q][0] += v0.x * a0 + v0.y * a1 + v0.z * a2 + v0.w * a3;
#pragma unroll
        for (int m = 1; m < 4; ++m) {
          float4 u = *(const float4*)&X[nb][m][k];
          acc[q][m] += u.x * b0 + u.y * b1 + u.z * b2 + u.w * b3;
        }
      }
    }
#pragma unroll
    for (int q = 0; q < 4; ++q)
#pragma unroll
      for (int m = 0; m < 4; ++m) Y[p * 4 + q][m][c] = acc[q][m];
  }
  __syncthreads();
  // ---- stage B: pointwise paths / species product (X := b) ----
#pragma unroll
  for (int q = 0; q < 4; ++q) {
    const int nb = p * 4 + q;
    const float a0 = Y[nb][0][c];
    const float ax = Y[nb][1][c], ay = Y[nb][2][c], az = Y[nb][3][c];
    const float dot = ax * ax + ay * ay + az * az;
    int sidx = 0;
#pragma unroll
    for (int si = 0; si < SS; ++si)
      if (at_s[nb][si] > 0.5f) sidx = si;
    const float a0sq = a0 * a0;
    const float b0v = Wprod0[(sidx * 5 + 0) * CC + c] * a0 +
                      Wprod0[(sidx * 5 + 1) * CC + c] * a0sq +
                      Wprod0[(sidx * 5 + 2) * CC + c] * dot +
                      Wprod0[(sidx * 5 + 3) * CC + c] * (a0sq * a0) +
                      Wprod0[(sidx * 5 + 4) * CC + c] * (a0 * dot);
    const float fac = Wprod1[(sidx * 4 + 0) * CC + c] +
                      Wprod1[(sidx * 4 + 1) * CC + c] * a0 +
                      Wprod1[(sidx * 4 + 2) * CC + c] * a0sq +
                      Wprod1[(sidx * 4 + 3) * CC + c] * dot;
    X[nb][0][c] = b0v;
    X[nb][1][c] = ax * fac;
    X[nb][2][c] = ay * fac;
    X[nb][3][c] = az * fac;
  }
  __syncthreads();
  // ---- stage H: h = b @ [Wp0 | Wp1] (Y := h) ----
  {
    float acc[4][4];
#pragma unroll
    for (int q = 0; q < 4; ++q)
#pragma unroll
      for (int m = 0; m < 4; ++m) acc[q][m] = 0.f;
    for (int k = 0; k < CC; k += 4) {
      const float a0 = Wp0[(k + 0) * CC + c], a1 = Wp0[(k + 1) * CC + c];
      const float a2 = Wp0[(k + 2) * CC + c], a3 = Wp0[(k + 3) * CC + c];
      const float b0 = Wp1[(k + 0) * CC + c], b1 = Wp1[(k + 1) * CC + c];
      const float b2 = Wp1[(k + 2) * CC + c], b3 = Wp1[(k + 3) * CC + c];
#pragma unroll
      for (int q = 0; q < 4; ++q) {
        const int nb = p * 4 + q;
        float4 v0 = *(const float4*)&X[nb][0][k];
        acc[q][0] += v0.x * a0 + v0.y * a1 + v0.z * a2 + v0.w * a3;
#pragma unroll
        for (int m = 1; m < 4; ++m) {
          float4 u = *(const float4*)&X[nb][m][k];
          acc[q][m] += u.x * b0 + u.y * b1 + u.z * b2 + u.w * b3;
        }
      }
    }
#pragma unroll
    for (int q = 0; q < 4; ++q)
#pragma unroll
      for (int m = 0; m < 4; ++m) Y[p * 4 + q][m][c] = acc[q][m];
  }
  __syncthreads();
  // ---- stage F: mh / gate / scalars / vec / nf ----
  if (t < 128) {
    const int nb = t >> 4, m = t & 15;
    float acc = 0.f;
    for (int k = 0; k < CC; ++k) acc += Y[nb][0][k] * Wr1[k * 16 + m];
    mh_s[nb][m] = silu_f(acc);
  }
  __syncthreads();
  if (t < 8) {
    float g = 0.f;
#pragma unroll
    for (int m = 0; m < 16; ++m) g += mh_s[t][m] * Wg[m];
    gate_s[t] = silu_f(g);
  }
#pragma unroll
  for (int q = 0; q < 4; ++q) {
    const int nb = p * 4 + q;
    float acc = 0.f;
#pragma unroll
    for (int m = 0; m < 16; ++m) acc += mh_s[nb][m] * Wr2[m * CC + c];
    out_scalars[(size_t)(n0 + nb) * CC + c] = acc;
  }
  __syncthreads();
  if (t < 24) {
    const int nb = t / 3, i = t % 3;
    float acc = 0.f;
    for (int k = 0; k < CC; ++k) acc += Y[nb][1 + i][k] * wv[k];
    out_vec[(size_t)(n0 + nb) * 3 + i] = acc * gate_s[nb];
  }
  for (int i = t; i < 4096; i += 256) out_nf[(size_t)n0 * 512 + i] = Yf[i];
}

extern "C" void kernel_launch(void* const* d_in, const int* in_sizes, int n_in,
                              void* d_out, int out_size, void* d_ws, size_t ws_size,
                              hipStream_t stream) {
  const float* vectors    = (const float*)d_in[0];
  const float* lengths    = (const float*)d_in[1];
  const float* node_feats = (const float*)d_in[2];
  const float* node_attrs = (const float*)d_in[3];
  const float* edge_feats = (const float*)d_in[4];
  const int*   edge_index = (const int*)d_in[5];
  const float* W_up       = (const float*)d_in[6];
  const float* radial_w1  = (const float*)d_in[7];
  const float* radial_b1  = (const float*)d_in[8];
  const float* radial_w2  = (const float*)d_in[9];
  const float* Wd0        = (const float*)d_in[10];
  const float* Wd1        = (const float*)d_in[11];
  const float* Wprod0     = (const float*)d_in[12];
  const float* Wprod1     = (const float*)d_in[13];
  const float* Wp0        = (const float*)d_in[14];
  const float* Wp1        = (const float*)d_in[15];
  const float* Wr1        = (const float*)d_in[16];
  const float* Wr2        = (const float*)d_in[17];
  const float* Wg         = (const float*)d_in[18];
  const float* wv         = (const float*)d_in[19];

  float* out = (float*)d_out;
  float* out_scalars = out;
  float* out_vec = out + (size_t)NN * CC;
  float* out_nf = out + (size_t)NN * CC + (size_t)NN * 3;
  float* sbuf = out_nf;        // s-scratch in the nf output region (N*512 floats)
  float* hbuf = out_scalars;   // h-scratch in the scalars output region (N*128):
                               // consumed by k_edge2, overwritten only at the
                               // END of k_down (stream-ordered, safe)

  // ws layout (~20.7 MB): cnt(=cur) | offs | edata(64B recs) | w2h | w2l
  int* cnt = (int*)d_ws;                              // NN
  int* offs = cnt + NN;                               // NN+4 (pad)
  float* edata = (float*)(offs + NN + 4);             // NE*16 floats
  unsigned short* w2h = (unsigned short*)(edata + (size_t)NE * 16);  // 16384
  unsigned short* w2l = w2h + 16384;                                 // 16384

  const int* senders = edge_index;
  const int* receivers = edge_index + NE;

  hipMemsetAsync(cnt, 0, NN * sizeof(int), stream);
  k_prep_w2<<<64, 256, 0, stream>>>(radial_w2, w2h, w2l);
  k_node_h<<<NN / 8, 128, 0, stream>>>(node_feats, W_up, hbuf);
  k_hist<<<NE / 256, 256, 0, stream>>>(receivers, cnt);
  k_scan2<<<1, 1024, 0, stream>>>(cnt, offs);
  k_fill2<<<NE / 256, 256, 0, stream>>>(receivers, senders, vectors, lengths,
                                        edge_feats, cnt, edata);
  k_edge2<<<NWIN, 256, 0, stream>>>(hbuf, radial_w1, radial_b1, w2h, w2l,
                                    offs, edata, sbuf);
  k_down<<<NN / 8, 256, 0, stream>>>(sbuf, node_attrs, Wd0, Wd1, Wprod0, Wprod1,
                                     Wp0, Wp1, Wr1, Wr2, Wg, wv,
                                     out_scalars, out_vec, out_nf);
}

// Round 6
// 396.852 us; speedup vs baseline: 1.7015x; 1.0916x over previous
//
#include <hip/hip_runtime.h>

#define NN 20000
#define NE 320000
#define CC 128
#define SS 10
#define NWIN 10000  // 2 nodes per window

typedef __attribute__((ext_vector_type(8))) short short8;
typedef __attribute__((ext_vector_type(4))) float f32x4;

#define MFMA16(a, b, c) __builtin_amdgcn_mfma_f32_16x16x32_bf16(a, b, c, 0, 0, 0)

__device__ __forceinline__ float silu_f(float x) { return x / (1.f + __expf(-x)); }

__device__ __forceinline__ unsigned short f2bf(float x) {  // RNE float->bf16 bits
  unsigned u = __float_as_uint(x);
  unsigned r = u + 0x7FFFu + ((u >> 16) & 1u);
  return (unsigned short)(r >> 16);
}
__device__ __forceinline__ float bf2f(unsigned short h) {
  return __uint_as_float(((unsigned)h) << 16);
}

// ---------------- prep: W2 -> transposed bf16 hi/lo [col][k] ----------------
__global__ __launch_bounds__(256) void k_prep_w2(const float* __restrict__ W2,
                                                 unsigned short* __restrict__ w2h,
                                                 unsigned short* __restrict__ w2l) {
  const int i = blockIdx.x * 256 + threadIdx.x;  // grid 64 -> 16384
  if (i < 64 * 256) {
    const int col = i % 256, k = i / 256;  // i == k*256+col
    const float x = W2[i];
    const unsigned short h = f2bf(x);
    w2h[col * 64 + k] = h;
    w2l[col * 64 + k] = f2bf(x - bf2f(h));
  }
}

// ---------------- h = node_feats @ W_up, 8 nodes per 128-thread block ----------------
__global__ __launch_bounds__(128) void k_node_h(const float* __restrict__ nf,
                                                const float* __restrict__ W,
                                                float* __restrict__ h) {
  __shared__ __align__(16) float rows[8][CC];
  const int c = threadIdx.x;
  const int n0 = blockIdx.x * 8;
#pragma unroll
  for (int q = 0; q < 8; ++q) rows[q][c] = nf[(n0 + q) * CC + c];
  __syncthreads();
  float acc[8] = {0.f, 0.f, 0.f, 0.f, 0.f, 0.f, 0.f, 0.f};
  for (int k = 0; k < CC; k += 4) {
    const float w0 = W[(k + 0) * CC + c];
    const float w1 = W[(k + 1) * CC + c];
    const float w2 = W[(k + 2) * CC + c];
    const float w3 = W[(k + 3) * CC + c];
#pragma unroll
    for (int q = 0; q < 8; ++q) {
      float4 v = *(const float4*)&rows[q][k];
      acc[q] += v.x * w0 + v.y * w1 + v.z * w2 + v.w * w3;
    }
  }
#pragma unroll
  for (int q = 0; q < 8; ++q) h[(n0 + q) * CC + c] = acc[q];
}

// ---------------- CSR build ----------------
__global__ void k_hist(const int* __restrict__ recv, int* __restrict__ cnt) {
  int i = blockIdx.x * blockDim.x + threadIdx.x;
  if (i < NE) atomicAdd(&cnt[recv[i]], 1);
}

// Single block, 1024 threads; each thread scans 20 contiguous counts.
__global__ __launch_bounds__(1024) void k_scan2(int* cntcur, int* offs) {
  const int t = threadIdx.x;
  int v[20];
  int tot = 0;
  if (t < 1000) {
#pragma unroll
    for (int i = 0; i < 20; ++i) {
      v[i] = cntcur[t * 20 + i];
      tot += v[i];
    }
  }
  const int lane = t & 63;
  int x = tot;
#pragma unroll
  for (int off = 1; off < 64; off <<= 1) {
    int y = __shfl_up(x, off, 64);
    if (lane >= off) x += y;
  }
  __shared__ int wt[16], wo[16];
  if (lane == 63) wt[t >> 6] = x;
  __syncthreads();
  if (t == 0) {
    int a = 0;
    for (int w = 0; w < 16; ++w) {
      wo[w] = a;
      a += wt[w];
    }
    offs[NN] = a;
  }
  __syncthreads();
  int run = wo[t >> 6] + x - tot;
  if (t < 1000) {
#pragma unroll
    for (int i = 0; i < 20; ++i) {
      offs[t * 20 + i] = run;
      cntcur[t * 20 + i] = run;
      run += v[i];
    }
  }
}

// Scatter edges into receiver-sorted 64B records:
// rec[0..2]=y1*sqrt3, rec[3]=len, rec[4..11]=efeat, int(rec[12])=sender
__global__ void k_fill2(const int* __restrict__ recv, const int* __restrict__ snd,
                        const float* __restrict__ vectors,
                        const float* __restrict__ lengths,
                        const float* __restrict__ efeat, int* __restrict__ cur,
                        float* __restrict__ edata) {
  int i = blockIdx.x * blockDim.x + threadIdx.x;
  if (i < NE) {
    const int r = recv[i];
    const int pos = atomicAdd(&cur[r], 1);
    const float vx = vectors[i * 3 + 0];
    const float vy = vectors[i * 3 + 1];
    const float vz = vectors[i * 3 + 2];
    const float nr = sqrtf(vx * vx + vy * vy + vz * vz) + 1e-9f;
    const float sc = 1.7320508075688772f / nr;
    float4 a = {vx * sc, vy * sc, vz * sc, lengths[i]};
    float4 b = *(const float4*)&efeat[(size_t)i * 8];
    float4 c = *(const float4*)&efeat[(size_t)i * 8 + 4];
    float4 d;
    ((int*)&d)[0] = snd[i];
    d.y = 0.f; d.z = 0.f; d.w = 0.f;
    float* rec = edata + (size_t)pos * 16;
    *(float4*)rec = a;
    *(float4*)(rec + 4) = b;
    *(float4*)(rec + 8) = c;
    *(float4*)(rec + 12) = d;
  }
}

// ---------------- pipelined 2-node-window edge aggregation ----------------
// Per 32-edge pass: [hid from ed[pb]] B1 [stage-write p+1 from regs; issue
// stage-loads p+2; consume pass p (MFMA + gather + reg accum)] B2.
// Stage loads ride a full pass ahead of use (T14); ed double-buffered;
// ed row stride 20 kills the stride-16 16-way bank conflict of r5.
__global__ __launch_bounds__(256) void k_edge3(
    const float* __restrict__ hbuf, const float* __restrict__ W1,
    const float* __restrict__ B1, const unsigned short* __restrict__ w2h,
    const unsigned short* __restrict__ w2l, const int* __restrict__ offs,
    const float* __restrict__ edata, float* __restrict__ sout) {
  __shared__ __align__(16) float W1s[9 * 64];
  __shared__ __align__(16) float B1s[64];
  __shared__ __align__(16) float ed[2][32][20];
  __shared__ __align__(16) unsigned short hidh[32][72];
  __shared__ __align__(16) unsigned short hidl[32][72];

  const int t = threadIdx.x;
  const int l = t & 63, wv = t >> 6, lg = l >> 4, lm = l & 15;
  const int half = wv & 1;
  const bool isw1 = wv >= 2;

  for (int i = t; i < 576; i += 256) W1s[i] = W1[i];
  if (t < 64) B1s[t] = B1[t];

  // B-frags: wave wv owns w-cols [wv*64, wv*64+64): col = wv*64+ct*16+lm,
  // k = s*32+lg*8+j (same formula as the A side -> shared perms cancel).
  short8 Bh[4][2], Bl[4][2];
#pragma unroll
  for (int ct = 0; ct < 4; ++ct)
#pragma unroll
    for (int s = 0; s < 2; ++s) {
      const int col = wv * 64 + ct * 16 + lm;
      Bh[ct][s] = *(const short8*)&w2h[col * 64 + s * 32 + lg * 8];
      Bl[ct][s] = *(const short8*)&w2l[col * 64 + s * 32 + lg * 8];
    }

  const int nb = blockIdx.x * 2;
  const int o0 = offs[nb], o1 = offs[nb + 1], o2 = offs[nb + 2];

  float p0[2][4] = {};
  float px[2][4] = {}, py[2][4] = {}, pz[2][4] = {};

  const int se = t >> 2, sq = t & 3;  // stage roles (t<128): edge, quad

  // ---- prologue: stage pass 0 into ed[0]; prefetch pass 1 into regs ----
  float4 sreg = {0.f, 0.f, 0.f, 0.f};
  if (t < 128) {
    const int idx = o0 + se;
    if (idx < o2) sreg = *(const float4*)&edata[(size_t)idx * 16 + sq * 4];
    *(float4*)&ed[0][se][sq * 4] = sreg;
    sreg = (float4){0.f, 0.f, 0.f, 0.f};
    const int idx1 = o0 + 32 + se;
    if (idx1 < o2) sreg = *(const float4*)&edata[(size_t)idx1 * 16 + sq * 4];
  }
  __syncthreads();  // W1s/B1s + ed[0] ready

#define CONSUME(GR, ACC, HC, YA, YB, YC)                                       \
  do {                                                                         \
    float vvv[4][4];                                                           \
    _Pragma("unroll") for (int ct = 0; ct < 4; ++ct)                           \
        _Pragma("unroll") for (int r = 0; r < 4; ++r)                          \
            vvv[ct][r] = (ACC)[ct][r] * (HC)[ct][r];                           \
    const bool fast0 = ((GR) + 16 <= o1);                                      \
    const bool fast1 = ((GR) >= o1) && ((GR) + 16 <= o2);                      \
    if (fast0) {                                                               \
      if (!isw1) {                                                             \
        _Pragma("unroll") for (int ct = 0; ct < 4; ++ct)                       \
            _Pragma("unroll") for (int r = 0; r < 4; ++r)                      \
                p0[0][ct] += vvv[ct][r];                                       \
      } else {                                                                 \
        _Pragma("unroll") for (int ct = 0; ct < 4; ++ct)                       \
            _Pragma("unroll") for (int r = 0; r < 4; ++r) {                    \
          px[0][ct] += vvv[ct][r] * (YA)[r];                                   \
          py[0][ct] += vvv[ct][r] * (YB)[r];                                   \
          pz[0][ct] += vvv[ct][r] * (YC)[r];                                   \
        }                                                                      \
      }                                                                        \
    } else if (fast1) {                                                        \
      if (!isw1) {                                                             \
        _Pragma("unroll") for (int ct = 0; ct < 4; ++ct)                       \
            _Pragma("unroll") for (int r = 0; r < 4; ++r)                      \
                p0[1][ct] += vvv[ct][r];                                       \
      } else {                                                                 \
        _Pragma("unroll") for (int ct = 0; ct < 4; ++ct)                       \
            _Pragma("unroll") for (int r = 0; r < 4; ++r) {                    \
          px[1][ct] += vvv[ct][r] * (YA)[r];                                   \
          py[1][ct] += vvv[ct][r] * (YB)[r];                                   \
          pz[1][ct] += vvv[ct][r] * (YC)[r];                                   \
        }                                                                      \
      }                                                                        \
    } else {                                                                   \
      const int grow0 = (GR) + lg * 4;                                         \
      _Pragma("unroll") for (int sl = 0; sl < 2; ++sl) {                       \
        const int slo = sl ? o1 : o0;                                          \
        const int shi = sl ? o2 : o1;                                          \
        if (shi > (GR) && slo < (GR) + 16) {                                   \
          if (!isw1) {                                                         \
            _Pragma("unroll") for (int r = 0; r < 4; ++r) {                    \
              const bool in = (grow0 + r >= slo) && (grow0 + r < shi);         \
              _Pragma("unroll") for (int ct = 0; ct < 4; ++ct)                 \
                  p0[sl][ct] += in ? vvv[ct][r] : 0.f;                         \
            }                                                                  \
          } else {                                                             \
            _Pragma("unroll") for (int r = 0; r < 4; ++r) {                    \
              const bool in = (grow0 + r >= slo) && (grow0 + r < shi);         \
              _Pragma("unroll") for (int ct = 0; ct < 4; ++ct) {               \
                const float m = in ? vvv[ct][r] : 0.f;                         \
                px[sl][ct] += m * (YA)[r];                                     \
                py[sl][ct] += m * (YB)[r];                                     \
                pz[sl][ct] += m * (YC)[r];                                     \
              }                                                                \
            }                                                                  \
          }                                                                    \
        }                                                                      \
      }                                                                        \
    }                                                                          \
  } while (0)

  const int npass = (o2 - o0 + 31) >> 5;
  for (int p = 0; p < npass; ++p) {
    const int pb = p & 1;
    const int base = o0 + p * 32;
    // ---- hid: thread t -> edge e=t&31, k-range [kseg*8, kseg*8+8) ----
    {
      const int e = t & 31, kseg = t >> 5;
      const int k0 = kseg * 8;
      float ef[9];
#pragma unroll
      for (int r = 0; r < 8; ++r) ef[r] = ed[pb][e][4 + r];
      ef[8] = ed[pb][e][3];
      float4 xa = *(const float4*)&B1s[k0];
      float4 xb = *(const float4*)&B1s[k0 + 4];
#pragma unroll
      for (int r = 0; r < 9; ++r) {
        const float4 wa = *(const float4*)&W1s[r * 64 + k0];
        const float4 wb = *(const float4*)&W1s[r * 64 + k0 + 4];
        xa.x += ef[r] * wa.x; xa.y += ef[r] * wa.y;
        xa.z += ef[r] * wa.z; xa.w += ef[r] * wa.w;
        xb.x += ef[r] * wb.x; xb.y += ef[r] * wb.y;
        xb.z += ef[r] * wb.z; xb.w += ef[r] * wb.w;
      }
      float xs[8];
      xs[0] = silu_f(xa.x); xs[1] = silu_f(xa.y);
      xs[2] = silu_f(xa.z); xs[3] = silu_f(xa.w);
      xs[4] = silu_f(xb.x); xs[5] = silu_f(xb.y);
      xs[6] = silu_f(xb.z); xs[7] = silu_f(xb.w);
      short8 ah, al;
#pragma unroll
      for (int j = 0; j < 8; ++j) {
        const unsigned short h = f2bf(xs[j]);
        ah[j] = (short)h;
        al[j] = (short)f2bf(xs[j] - bf2f(h));
      }
      *(short8*)&hidh[e][k0] = ah;
      *(short8*)&hidl[e][k0] = al;
      // dead edges (idx>=o2): ed zeroed -> finite garbage; masked in consume
    }
    __syncthreads();  // B1: hid ready; consume(p-1) finished (prev B2)
    // ---- stage-write pass p+1; prefetch pass p+2 ----
    if (t < 128) {
      *(float4*)&ed[pb ^ 1][se][sq * 4] = sreg;
      sreg = (float4){0.f, 0.f, 0.f, 0.f};
      const int idx2 = base + 64 + se;
      if (idx2 < o2) sreg = *(const float4*)&edata[(size_t)idx2 * 16 + sq * 4];
    }
    // ---- consume pass p ----
    {
      // subtile 0 (rows base..base+15)
      int sd0[4];
      float ya0[4], yb0[4], yc0[4];
#pragma unroll
      for (int r = 0; r < 4; ++r) {
        const int row = lg * 4 + r;
        sd0[r] = __float_as_int(ed[pb][row][12]);
        ya0[r] = ed[pb][row][0];
        yb0[r] = ed[pb][row][1];
        yc0[r] = ed[pb][row][2];
      }
      float hc0[4][4];
#pragma unroll
      for (int ct = 0; ct < 4; ++ct) {
        const int col = half * 64 + ct * 16 + lm;
#pragma unroll
        for (int r = 0; r < 4; ++r) hc0[ct][r] = hbuf[(size_t)sd0[r] * CC + col];
      }
      short8 Ah0 = *(const short8*)&hidh[lm][lg * 8];
      short8 Ah1 = *(const short8*)&hidh[lm][32 + lg * 8];
      short8 Al0 = *(const short8*)&hidl[lm][lg * 8];
      short8 Al1 = *(const short8*)&hidl[lm][32 + lg * 8];
      f32x4 acc0[4];
#pragma unroll
      for (int ct = 0; ct < 4; ++ct) {
        f32x4 a = {0.f, 0.f, 0.f, 0.f};
        a = MFMA16(Ah0, Bh[ct][0], a);
        a = MFMA16(Ah0, Bl[ct][0], a);
        a = MFMA16(Al0, Bh[ct][0], a);
        a = MFMA16(Ah1, Bh[ct][1], a);
        a = MFMA16(Ah1, Bl[ct][1], a);
        a = MFMA16(Al1, Bh[ct][1], a);
        acc0[ct] = a;
      }
      const bool live1 = (base + 16) < o2;
      if (live1) {
        // subtile 1: issue meta + gathers under subtile-0 math
        int sd1[4];
        float ya1[4], yb1[4], yc1[4];
#pragma unroll
        for (int r = 0; r < 4; ++r) {
          const int row = 16 + lg * 4 + r;
          sd1[r] = __float_as_int(ed[pb][row][12]);
          ya1[r] = ed[pb][row][0];
          yb1[r] = ed[pb][row][1];
          yc1[r] = ed[pb][row][2];
        }
        float hc1[4][4];
#pragma unroll
        for (int ct = 0; ct < 4; ++ct) {
          const int col = half * 64 + ct * 16 + lm;
#pragma unroll
          for (int r = 0; r < 4; ++r) hc1[ct][r] = hbuf[(size_t)sd1[r] * CC + col];
        }
        CONSUME(base, acc0, hc0, ya0, yb0, yc0);
        short8 Bh0_ = *(const short8*)&hidh[16 + lm][lg * 8];
        short8 Bh1_ = *(const short8*)&hidh[16 + lm][32 + lg * 8];
        short8 Bl0_ = *(const short8*)&hidl[16 + lm][lg * 8];
        short8 Bl1_ = *(const short8*)&hidl[16 + lm][32 + lg * 8];
        f32x4 acc1[4];
#pragma unroll
        for (int ct = 0; ct < 4; ++ct) {
          f32x4 a = {0.f, 0.f, 0.f, 0.f};
          a = MFMA16(Bh0_, Bh[ct][0], a);
          a = MFMA16(Bh0_, Bl[ct][0], a);
          a = MFMA16(Bl0_, Bh[ct][0], a);
          a = MFMA16(Bh1_, Bh[ct][1], a);
          a = MFMA16(Bh1_, Bl[ct][1], a);
          a = MFMA16(Bl1_, Bh[ct][1], a);
          acc1[ct] = a;
        }
        CONSUME(base + 16, acc1, hc1, ya1, yb1, yc1);
      } else {
        CONSUME(base, acc0, hc0, ya0, yb0, yc0);
      }
    }
    __syncthreads();  // B2: pass closed (ed[pb], hidh free)
  }
#undef CONSUME

  // flush: reduce over lane groups (l, l^16, l^32, l^48 share a column)
  const float inv = 1.f / 16.f;
#pragma unroll
  for (int sl = 0; sl < 2; ++sl) {
    const int n = nb + sl;
    if (!isw1) {
#pragma unroll
      for (int ct = 0; ct < 4; ++ct) {
        float v = p0[sl][ct];
        v += __shfl_xor(v, 16, 64);
        v += __shfl_xor(v, 32, 64);
        if (lg == 0) sout[(size_t)n * 512 + half * 64 + ct * 16 + lm] = v * inv;
      }
    } else {
#pragma unroll
      for (int ct = 0; ct < 4; ++ct) {
        float vx = px[sl][ct], vy = py[sl][ct], vz = pz[sl][ct];
        vx += __shfl_xor(vx, 16, 64); vx += __shfl_xor(vx, 32, 64);
        vy += __shfl_xor(vy, 16, 64); vy += __shfl_xor(vy, 32, 64);
        vz += __shfl_xor(vz, 16, 64); vz += __shfl_xor(vz, 32, 64);
        if (lg == 0) {
          const int c = half * 64 + ct * 16 + lm;
          sout[(size_t)n * 512 + 128 + c] = vx * inv;
          sout[(size_t)n * 512 + 256 + c] = vy * inv;
          sout[(size_t)n * 512 + 384 + c] = vz * inv;
        }
      }
    }
  }
}

// ---------------- fused downstream: 8 nodes per 256-thread block ----------------
__global__ __launch_bounds__(256) void k_down(
    const float* __restrict__ sbuf, const float* __restrict__ attrs,
    const float* __restrict__ Wd0, const float* __restrict__ Wd1,
    const float* __restrict__ Wprod0, const float* __restrict__ Wprod1,
    const float* __restrict__ Wp0, const float* __restrict__ Wp1,
    const float* __restrict__ Wr1, const float* __restrict__ Wr2,
    const float* __restrict__ Wg, const float* __restrict__ wv,
    float* __restrict__ out_scalars, float* __restrict__ out_vec,
    float* __restrict__ out_nf) {
  __shared__ __align__(16) float X[8][4][CC];  // s, then b
  __shared__ __align__(16) float Y[8][4][CC];  // a, then h
  __shared__ float at_s[8][SS];
  __shared__ float mh_s[8][16];
  __shared__ float gate_s[8];
  const int t = threadIdx.x;
  const int c = t & 127, p = t >> 7;
  const int n0 = blockIdx.x * 8;
  float* Xf = &X[0][0][0];
  float* Yf = &Y[0][0][0];
  for (int i = t; i < 4096; i += 256) Xf[i] = sbuf[(size_t)n0 * 512 + i];
  for (int i = t; i < 8 * SS; i += 256) at_s[i / SS][i % SS] = attrs[n0 * SS + i];
  __syncthreads();
  // ---- stage A: a = s @ [Wd0 | Wd1] ----
  {
    float acc[4][4];
#pragma unroll
    for (int q = 0; q < 4; ++q)
#pragma unroll
      for (int m = 0; m < 4; ++m) acc[q][m] = 0.f;
    for (int k = 0; k < CC; k += 4) {
      const float a0 = Wd0[(k + 0) * CC + c], a1 = Wd0[(k + 1) * CC + c];
      const float a2 = Wd0[(k + 2) * CC + c], a3 = Wd0[(k + 3) * CC + c];
      const float b0 = Wd1[(k + 0) * CC + c], b1 = Wd1[(k + 1) * CC + c];
      const float b2 = Wd1[(k + 2) * CC + c], b3 = Wd1[(k + 3) * CC + c];
#pragma unroll
      for (int q = 0; q < 4; ++q) {
        const int nb = p * 4 + q;
        float4 v0 = *(const float4*)&X[nb][0][k];
        acc[q][0] += v0.x * a0 + v0.y * a1 + v0.z * a2 + v0.w * a3;
#pragma unroll
        for (int m = 1; m < 4; ++m) {
          float4 u = *(const float4*)&X[nb][m][k];
          acc[q][m] += u.x * b0 + u.y * b1 + u.z * b2 + u.w * b3;
        }
      }
    }
#pragma unroll
    for (int q = 0; q < 4; ++q)
#pragma unroll
      for (int m = 0; m < 4; ++m) Y[p * 4 + q][m][c] = acc[q][m];
  }
  __syncthreads();
  // ---- stage B: pointwise paths / species product (X := b) ----
#pragma unroll
  for (int q = 0; q < 4; ++q) {
    const int nb = p * 4 + q;
    const float a0 = Y[nb][0][c];
    const float ax = Y[nb][1][c], ay = Y[nb][2][c], az = Y[nb][3][c];
    const float dot = ax * ax + ay * ay + az * az;
    int sidx = 0;
#pragma unroll
    for (int si = 0; si < SS; ++si)
      if (at_s[nb][si] > 0.5f) sidx = si;
    const float a0sq = a0 * a0;
    const float b0v = Wprod0[(sidx * 5 + 0) * CC + c] * a0 +
                      Wprod0[(sidx * 5 + 1) * CC + c] * a0sq +
                      Wprod0[(sidx * 5 + 2) * CC + c] * dot +
                      Wprod0[(sidx * 5 + 3) * CC + c] * (a0sq * a0) +
                      Wprod0[(sidx * 5 + 4) * CC + c] * (a0 * dot);
    const float fac = Wprod1[(sidx * 4 + 0) * CC + c] +
                      Wprod1[(sidx * 4 + 1) * CC + c] * a0 +
                      Wprod1[(sidx * 4 + 2) * CC + c] * a0sq +
                      Wprod1[(sidx * 4 + 3) * CC + c] * dot;
    X[nb][0][c] = b0v;
    X[nb][1][c] = ax * fac;
    X[nb][2][c] = ay * fac;
    X[nb][3][c] = az * fac;
  }
  __syncthreads();
  // ---- stage H: h = b @ [Wp0 | Wp1] (Y := h) ----
  {
    float acc[4][4];
#pragma unroll
    for (int q = 0; q < 4; ++q)
#pragma unroll
      for (int m = 0; m < 4; ++m) acc[q][m] = 0.f;
    for (int k = 0; k < CC; k += 4) {
      const float a0 = Wp0[(k + 0) * CC + c], a1 = Wp0[(k + 1) * CC + c];
      const float a2 = Wp0[(k + 2) * CC + c], a3 = Wp0[(k + 3) * CC + c];
      const float b0 = Wp1[(k + 0) * CC + c], b1 = Wp1[(k + 1) * CC + c];
      const float b2 = Wp1[(k + 2) * CC + c], b3 = Wp1[(k + 3) * CC + c];
#pragma unroll
      for (int q = 0; q < 4; ++q) {
        const int nb = p * 4 + q;
        float4 v0 = *(const float4*)&X[nb][0][k];
        acc[q][0] += v0.x * a0 + v0.y * a1 + v0.z * a2 + v0.w * a3;
#pragma unroll
        for (int m = 1; m < 4; ++m) {
          float4 u = *(const float4*)&X[nb][m][k];
          acc[q][m] += u.x * b0 + u.y * b1 + u.z * b2 + u.w * b3;
        }
      }
    }
#pragma unroll
    for (int q = 0; q < 4; ++q)
#pragma unroll
      for (int m = 0; m < 4; ++m) Y[p * 4 + q][m][c] = acc[q][m];
  }
  __syncthreads();
  // ---- stage F: mh / gate / scalars / vec / nf ----
  if (t < 128) {
    const int nb = t >> 4, m = t & 15;
    float acc = 0.f;
    for (int k = 0; k < CC; ++k) acc += Y[nb][0][k] * Wr1[k * 16 + m];
    mh_s[nb][m] = silu_f(acc);
  }
  __syncthreads();
  if (t < 8) {
    float g = 0.f;
#pragma unroll
    for (int m = 0; m < 16; ++m) g += mh_s[t][m] * Wg[m];
    gate_s[t] = silu_f(g);
  }
#pragma unroll
  for (int q = 0; q < 4; ++q) {
    const int nb = p * 4 + q;
    float acc = 0.f;
#pragma unroll
    for (int m = 0; m < 16; ++m) acc += mh_s[nb][m] * Wr2[m * CC + c];
    out_scalars[(size_t)(n0 + nb) * CC + c] = acc;
  }
  __syncthreads();
  if (t < 24) {
    const int nb = t / 3, i = t % 3;
    float acc = 0.f;
    for (int k = 0; k < CC; ++k) acc += Y[nb][1 + i][k] * wv[k];
    out_vec[(size_t)(n0 + nb) * 3 + i] = acc * gate_s[nb];
  }
  for (int i = t; i < 4096; i += 256) out_nf[(size_t)n0 * 512 + i] = Yf[i];
}

extern "C" void kernel_launch(void* const* d_in, const int* in_sizes, int n_in,
                              void* d_out, int out_size, void* d_ws, size_t ws_size,
                              hipStream_t stream) {
  const float* vectors    = (const float*)d_in[0];
  const float* lengths    = (const float*)d_in[1];
  const float* node_feats = (const float*)d_in[2];
  const float* node_attrs = (const float*)d_in[3];
  const float* edge_feats = (const float*)d_in[4];
  const int*   edge_index = (const int*)d_in[5];
  const float* W_up       = (const float*)d_in[6];
  const float* radial_w1  = (const float*)d_in[7];
  const float* radial_b1  = (const float*)d_in[8];
  const float* radial_w2  = (const float*)d_in[9];
  const float* Wd0        = (const float*)d_in[10];
  const float* Wd1        = (const float*)d_in[11];
  const float* Wprod0     = (const float*)d_in[12];
  const float* Wprod1     = (const float*)d_in[13];
  const float* Wp0        = (const float*)d_in[14];
  const float* Wp1        = (const float*)d_in[15];
  const float* Wr1        = (const float*)d_in[16];
  const float* Wr2        = (const float*)d_in[17];
  const float* Wg         = (const float*)d_in[18];
  const float* wv         = (const float*)d_in[19];

  float* out = (float*)d_out;
  float* out_scalars = out;
  float* out_vec = out + (size_t)NN * CC;
  float* out_nf = out + (size_t)NN * CC + (size_t)NN * 3;
  float* sbuf = out_nf;        // s-scratch in the nf output region (N*512 floats)
  float* hbuf = out_scalars;   // h-scratch in the scalars output region (N*128):
                               // consumed by k_edge3, overwritten only at the
                               // END of k_down (stream-ordered, safe)

  // ws layout (~20.7 MB): cnt(=cur) | offs | edata(64B recs) | w2h | w2l
  int* cnt = (int*)d_ws;                              // NN
  int* offs = cnt + NN;                               // NN+4 (pad)
  float* edata = (float*)(offs + NN + 4);             // NE*16 floats
  unsigned short* w2h = (unsigned short*)(edata + (size_t)NE * 16);  // 16384
  unsigned short* w2l = w2h + 16384;                                 // 16384

  const int* senders = edge_index;
  const int* receivers = edge_index + NE;

  hipMemsetAsync(cnt, 0, NN * sizeof(int), stream);
  k_prep_w2<<<64, 256, 0, stream>>>(radial_w2, w2h, w2l);
  k_node_h<<<NN / 8, 128, 0, stream>>>(node_feats, W_up, hbuf);
  k_hist<<<NE / 256, 256, 0, stream>>>(receivers, cnt);
  k_scan2<<<1, 1024, 0, stream>>>(cnt, offs);
  k_fill2<<<NE / 256, 256, 0, stream>>>(receivers, senders, vectors, lengths,
                                        edge_feats, cnt, edata);
  k_edge3<<<NWIN, 256, 0, stream>>>(hbuf, radial_w1, radial_b1, w2h, w2l,
                                    offs, edata, sbuf);
  k_down<<<NN / 8, 256, 0, stream>>>(sbuf, node_attrs, Wd0, Wd1, Wprod0, Wprod1,
                                     Wp0, Wp1, Wr1, Wr2, Wg, wv,
                                     out_scalars, out_vec, out_nf);
}